// Round 5
// baseline (331.161 us; speedup 1.0000x reference)
//
#include <hip/hip_runtime.h>
#include <hip/hip_bf16.h>

#define N_ 2
#define L_ 512
#define RD_ 128
#define PD_ 64
#define H_ 12
#define NL_ (N_*L_)
#define POUT_ 2016          /* 3*384 + 3*288 */
#define FEAT_ 1824
#define INF_ 100000.0f
#define ISQD_ 0.17677669529663687f   /* 1/sqrt(32) */
#define ISQ3_ 0.5773502691896258f    /* sqrt(1/3) */
#define LL_ ((size_t)L_*L_)

// ---------------------------------------------------------------------------
// K1: projection GEMM. proj[token][2016] = resf @ [Wq|Wk|Wv|Wqp|Wkp|Wvp]^T
// ---------------------------------------------------------------------------
__global__ __launch_bounds__(256) void k_proj_gemm(
    const float* __restrict__ resf,
    const float* __restrict__ Wq, const float* __restrict__ Wk, const float* __restrict__ Wv,
    const float* __restrict__ Wqp, const float* __restrict__ Wkp, const float* __restrict__ Wvp,
    float* __restrict__ proj)
{
  const int rb = blockIdx.x * 8;
  const int ob = blockIdx.y * 128;
  const int tid = threadIdx.x;
  __shared__ float xt[8*132];
  __shared__ float wt[128*132];
  {
    int r = tid >> 5, kq = (tid & 31) * 4;
    float4 v = *(const float4*)(resf + (size_t)(rb + r)*RD_ + kq);
    xt[r*132+kq]=v.x; xt[r*132+kq+1]=v.y; xt[r*132+kq+2]=v.z; xt[r*132+kq+3]=v.w;
  }
  for (int m = 0; m < 16; ++m) {
    int idx = m*256 + tid;
    int r = idx >> 5, kq = (idx & 31) * 4;
    int o = ob + r;
    float4 v;
    if (o < 384)        v = *(const float4*)(Wq  + (size_t)o*RD_ + kq);
    else if (o < 768)   v = *(const float4*)(Wk  + (size_t)(o-384)*RD_ + kq);
    else if (o < 1152)  v = *(const float4*)(Wv  + (size_t)(o-768)*RD_ + kq);
    else if (o < 1440)  v = *(const float4*)(Wqp + (size_t)(o-1152)*RD_ + kq);
    else if (o < 1728)  v = *(const float4*)(Wkp + (size_t)(o-1440)*RD_ + kq);
    else if (o < POUT_) v = *(const float4*)(Wvp + (size_t)(o-1728)*RD_ + kq);
    else                v = make_float4(0.f,0.f,0.f,0.f);
    wt[r*132+kq]=v.x; wt[r*132+kq+1]=v.y; wt[r*132+kq+2]=v.z; wt[r*132+kq+3]=v.w;
  }
  __syncthreads();
  const int tt = tid & 7, g = tid >> 3;
  float acc0=0.f, acc1=0.f, acc2=0.f, acc3=0.f;
  #pragma unroll 4
  for (int k2 = 0; k2 < RD_; ++k2) {
    float xv = xt[tt*132 + k2];
    acc0 += xv * wt[(g     )*132 + k2];
    acc1 += xv * wt[(g + 32)*132 + k2];
    acc2 += xv * wt[(g + 64)*132 + k2];
    acc3 += xv * wt[(g + 96)*132 + k2];
  }
  float* dst = proj + (size_t)(rb + tt)*POUT_ + ob;
  if (ob + g      < POUT_) dst[g]      = acc0;
  if (ob + g + 32 < POUT_) dst[g+32]   = acc1;
  if (ob + g + 64 < POUT_) dst[g+64]   = acc2;
  if (ob + g + 96 < POUT_) dst[g+96]   = acc3;
}

// ---------------------------------------------------------------------------
// K2: per-token rotate + build Q~/K~ (58-dim augmented, padded to 64)
// ---------------------------------------------------------------------------
__global__ __launch_bounds__(64) void k_rot(
    const float* __restrict__ R, const float* __restrict__ coord,
    const float* __restrict__ spc, const float* __restrict__ proj,
    float* __restrict__ qt, float* __restrict__ kt, float* __restrict__ vpg)
{
  const int t = blockIdx.x;
  const int n = t / L_, i = t % L_;
  const int tid = threadIdx.x;
  __shared__ float prow[POUT_];
  __shared__ float qpl[288], kpl[288], vpl[288];
  __shared__ float qqs[H_], kks[H_], coefs[H_];
  for (int m = tid; m < POUT_/4; m += 64)
    ((float4*)prow)[m] = *((const float4*)(proj + (size_t)t*POUT_) + m);
  if (tid < H_) coefs[tid] = -log1pf(expf(spc[tid])) * (1.0f/12.0f);
  __syncthreads();
  const float* Rm = R + (size_t)t*9;
  const float r00=Rm[0],r01=Rm[1],r02=Rm[2],r10=Rm[3],r11=Rm[4],r12=Rm[5],r20=Rm[6],r21=Rm[7],r22=Rm[8];
  const float cx = coord[(size_t)t*3], cy = coord[(size_t)t*3+1], cz = coord[(size_t)t*3+2];
  for (int idx = tid; idx < 288; idx += 64) {
    int mat = idx / 96, p = idx % 96;
    const float* s = prow + 1152 + mat*288 + p*3;
    float px=s[0], py=s[1], pz=s[2];
    float gx = r00*px + r01*py + r02*pz + cx;
    float gy = r10*px + r11*py + r12*pz + cy;
    float gz = r20*px + r21*py + r22*pz + cz;
    float* d = (mat==0? qpl : mat==1? kpl : vpl) + p*3;
    d[0]=gx; d[1]=gy; d[2]=gz;
  }
  __syncthreads();
  if (tid < 24) {
    int mat = tid / H_, h = tid % H_;
    const float* s = (mat==0? qpl : kpl) + h*24;
    float acc = 0.f;
    #pragma unroll
    for (int c2 = 0; c2 < 24; ++c2) acc += s[c2]*s[c2];
    (mat==0? qqs : kks)[h] = acc;
  }
  for (int m = tid; m < 72; m += 64)
    ((float4*)(vpg + (size_t)t*288))[m] = ((float4*)vpl)[m];
  __syncthreads();
  for (int idx = tid; idx < 2*H_*64; idx += 64) {
    int which = idx / 768, rem = idx % 768, h = rem >> 6, c = rem & 63;
    float val;
    if (which == 0) {
      if (c < 32)       val = prow[h*32 + c] * ISQD_;
      else if (c < 56)  val = qpl[h*24 + (c-32)] * (-2.0f * coefs[h]);
      else if (c == 56) val = coefs[h] * qqs[h];
      else if (c == 57) val = coefs[h];
      else              val = 0.f;
      qt[((size_t)(n*H_ + h)*L_ + i)*64 + c] = val;
    } else {
      if (c < 32)       val = prow[384 + h*32 + c];
      else if (c < 56)  val = kpl[h*24 + (c-32)];
      else if (c == 56) val = 1.0f;
      else if (c == 57) val = kks[h];
      else              val = 0.f;
      kt[((size_t)(n*H_ + h)*L_ + i)*64 + c] = val;
    }
  }
}

// ---------------------------------------------------------------------------
// K3: logits GEMM (node+spatial): lgal[n][h][i][j] = Qt[i] . Kt[j]  (raw)
// ---------------------------------------------------------------------------
__global__ __launch_bounds__(256) void k_lgns(
    const float* __restrict__ qt, const float* __restrict__ kt,
    float* __restrict__ lgal)
{
  const int jb = blockIdx.x * 64, ib = blockIdx.y * 64, nh = blockIdx.z;
  const int tid = threadIdx.x;
  __shared__ float qs[64*65], ks[64*65];
  for (int m = 0; m < 4; ++m) {
    int idx = m*256 + tid;
    int r = idx >> 4, kq = (idx & 15) * 4;
    float4 a = *(const float4*)(qt + ((size_t)nh*L_ + ib + r)*64 + kq);
    qs[r*65+kq]=a.x; qs[r*65+kq+1]=a.y; qs[r*65+kq+2]=a.z; qs[r*65+kq+3]=a.w;
    float4 b = *(const float4*)(kt + ((size_t)nh*L_ + jb + r)*64 + kq);
    ks[r*65+kq]=b.x; ks[r*65+kq+1]=b.y; ks[r*65+kq+2]=b.z; ks[r*65+kq+3]=b.w;
  }
  __syncthreads();
  const int tx = tid & 15, ty = tid >> 4;
  const int i0 = ty*4, j0 = tx*4;
  float acc[4][4] = {};
  #pragma unroll 2
  for (int k2 = 0; k2 < 64; ++k2) {
    float qv[4], kv[4];
    #pragma unroll
    for (int d = 0; d < 4; ++d) { qv[d] = qs[(i0+d)*65 + k2]; kv[d] = ks[(j0+d)*65 + k2]; }
    #pragma unroll
    for (int a2 = 0; a2 < 4; ++a2)
      #pragma unroll
      for (int b2 = 0; b2 < 4; ++b2) acc[a2][b2] += qv[a2]*kv[b2];
  }
  #pragma unroll
  for (int a2 = 0; a2 < 4; ++a2) {
    float4 v = make_float4(acc[a2][0], acc[a2][1], acc[a2][2], acc[a2][3]);
    *(float4*)(lgal + ((size_t)nh*L_ + ib + i0 + a2)*L_ + jb + j0) = v;
  }
}

// ---------------------------------------------------------------------------
// K4: pair bias + mask + scale (RMW lgal). Block = (jt 64, i, n); 32/CU.
// lane = j-row (stride-67 LDS = conflict-free), wave = head-triple {w,w+4,w+8}
// (readfirstlane -> Wpb stays in SGPRs). The single HBM pass over pair.
// ---------------------------------------------------------------------------
__global__ __launch_bounds__(256) void k_pbias(
    const float* __restrict__ pair, const int* __restrict__ mask,
    const float* __restrict__ Wpb, float* __restrict__ lgal)
{
  const int jt = blockIdx.x, i = blockIdx.y, n = blockIdx.z;
  const int bi = n*L_ + i;
  const int tid = threadIdx.x;
  __shared__ float pt[64*67];
  for (int m = 0; m < 4; ++m) {
    int idx = m*256 + tid;
    int r = idx >> 4, cq = (idx & 15)*4;
    float4 v = *(const float4*)(pair + ((size_t)bi*L_ + jt*64 + r)*PD_ + cq);
    float* d = pt + r*67 + cq;
    d[0]=v.x; d[1]=v.y; d[2]=v.z; d[3]=v.w;
  }
  __syncthreads();
  const int r = tid & 63;
  const int w = __builtin_amdgcn_readfirstlane(tid >> 6);
  const int j = jt*64 + r;
  const float* pr = pt + r*67;
  const float* w0 = Wpb + (w    )*64;
  const float* w1 = Wpb + (w + 4)*64;
  const float* w2 = Wpb + (w + 8)*64;
  float a0=0.f, a1=0.f, a2=0.f;
  #pragma unroll 16
  for (int c = 0; c < 64; ++c) {
    float pv = pr[c];
    a0 += pv*w0[c]; a1 += pv*w1[c]; a2 += pv*w2[c];
  }
  const int mi = mask[bi];
  const float mt = (mi && mask[n*L_ + j]) ? 0.f : -INF_;
  size_t base = ((size_t)(n*H_ + w)*L_ + i)*L_ + j;
  float l0 = lgal[base];
  float l1 = lgal[base + 4*LL_];
  float l2 = lgal[base + 8*LL_];
  lgal[base         ] = (l0 + a0)*ISQ3_ + mt;
  lgal[base + 4*LL_ ] = (l1 + a1)*ISQ3_ + mt;
  lgal[base + 8*LL_ ] = (l2 + a2)*ISQ3_ + mt;
}

// ---------------------------------------------------------------------------
// K5: softmax per (n,h,i) row, one wave per row, row held in registers.
// ---------------------------------------------------------------------------
__global__ __launch_bounds__(256) void k_softx(
    const int* __restrict__ mask, float* __restrict__ lgal)
{
  const int tid = threadIdx.x;
  const int wid = tid >> 6, lane = tid & 63;
  const int rid = blockIdx.x*4 + wid;          // (n*H+h)*L + i
  const int i = rid & (L_-1);
  const int nh = rid >> 9;
  const int n = nh / H_;
  float4* r4 = (float4*)(lgal + (size_t)rid * L_);
  float4 p0 = r4[lane], p1 = r4[lane + 64];
  float mx = fmaxf(fmaxf(fmaxf(p0.x,p0.y),fmaxf(p0.z,p0.w)),
                   fmaxf(fmaxf(p1.x,p1.y),fmaxf(p1.z,p1.w)));
  #pragma unroll
  for (int off = 1; off < 64; off <<= 1) mx = fmaxf(mx, __shfl_xor(mx, off, 64));
  p0.x = expf(p0.x - mx); p0.y = expf(p0.y - mx);
  p0.z = expf(p0.z - mx); p0.w = expf(p0.w - mx);
  p1.x = expf(p1.x - mx); p1.y = expf(p1.y - mx);
  p1.z = expf(p1.z - mx); p1.w = expf(p1.w - mx);
  float s = p0.x+p0.y+p0.z+p0.w + p1.x+p1.y+p1.z+p1.w;
  #pragma unroll
  for (int off = 1; off < 64; off <<= 1) s += __shfl_xor(s, off, 64);
  const float inv = (mask[n*L_ + i] ? 1.f : 0.f) / s;
  p0.x*=inv; p0.y*=inv; p0.z*=inv; p0.w*=inv;
  p1.x*=inv; p1.y*=inv; p1.z*=inv; p1.w*=inv;
  r4[lane] = p0; r4[lane + 64] = p1;
}

// ---------------------------------------------------------------------------
// K6: feat_pair partials. Block = (jt 256, i, n), 4 waves; lane = c,
// wave = head-triple; alpha via wave-uniform s_loads; pair from L3.
// part[(bi*2+jt)*768 + h*64 + c]
// ---------------------------------------------------------------------------
__global__ __launch_bounds__(256) void k_paggr(
    const float* __restrict__ pair, const float* __restrict__ lgal,
    float* __restrict__ part)
{
  const int jt = blockIdx.x, i = blockIdx.y, n = blockIdx.z;
  const int bi = n*L_ + i;
  const int tid = threadIdx.x;
  __shared__ float pt[64*67];
  const int lane = tid & 63;
  const int w = __builtin_amdgcn_readfirstlane(tid >> 6);
  const float* a0 = lgal + ((size_t)(n*H_ + w    )*L_ + i)*L_ + jt*256;
  const float* a1 = lgal + ((size_t)(n*H_ + w + 4)*L_ + i)*L_ + jt*256;
  const float* a2 = lgal + ((size_t)(n*H_ + w + 8)*L_ + i)*L_ + jt*256;
  float acc0=0.f, acc1=0.f, acc2=0.f;
  for (int sub = 0; sub < 4; ++sub) {
    __syncthreads();
    for (int m = 0; m < 4; ++m) {
      int idx = m*256 + tid;
      int r = idx >> 4, cq = (idx & 15)*4;
      float4 v = *(const float4*)(pair + ((size_t)bi*L_ + jt*256 + sub*64 + r)*PD_ + cq);
      float* d = pt + r*67 + cq;
      d[0]=v.x; d[1]=v.y; d[2]=v.z; d[3]=v.w;
    }
    __syncthreads();
    const int jo = sub*64;
    #pragma unroll 8
    for (int j2 = 0; j2 < 64; ++j2) {
      float pv = pt[j2*67 + lane];
      acc0 += pv * a0[jo + j2];
      acc1 += pv * a1[jo + j2];
      acc2 += pv * a2[jo + j2];
    }
  }
  float* dst = part + ((size_t)bi*2 + jt)*768;
  dst[(w    )*64 + lane] = acc0;
  dst[(w + 4)*64 + lane] = acc1;
  dst[(w + 8)*64 + lane] = acc2;
}

// ---------------------------------------------------------------------------
// K7: reduce 2 partials -> feat[token][0..767]
// ---------------------------------------------------------------------------
__global__ __launch_bounds__(256) void k_pred(
    const float* __restrict__ part, float* __restrict__ feat)
{
  const int tok = blockIdx.x, tid = threadIdx.x;
  const float* p0 = part + (size_t)tok*2*768;
  const float* p1 = p0 + 768;
  float* fb = feat + (size_t)tok*FEAT_;
  #pragma unroll
  for (int m = 0; m < 3; ++m) {
    int f = m*256 + tid;
    fb[f] = p0[f] + p1[f];
  }
}

// ---------------------------------------------------------------------------
// K8: per (n,h) GEMM: C[i, 0:56] = alpha[i,j] @ [v | vp][j, 0:56]
// ---------------------------------------------------------------------------
__global__ __launch_bounds__(256) void k_av(
    const float* __restrict__ lgal, const float* __restrict__ proj,
    const float* __restrict__ vpg,
    float* __restrict__ feat, float* __restrict__ aggr)
{
  const int ib = blockIdx.x * 64;
  const int nh = blockIdx.y;
  const int n = nh / H_, h = nh % H_, nL = n*L_;
  const int tid = threadIdx.x;
  __shared__ float as[64*65];
  __shared__ float bs[64*60];
  const int tx = tid & 15, ty = tid >> 4;
  const int i0 = ty*4, c0 = tx*4;
  float acc[4][4] = {};
  for (int jb = 0; jb < 512; jb += 64) {
    for (int m = 0; m < 4; ++m) {
      int idx = m*256 + tid;
      int r = idx >> 4, jq = (idx & 15) * 4;
      float4 a = *(const float4*)(lgal + ((size_t)nh*L_ + ib + r)*L_ + jb + jq);
      as[r*65+jq]=a.x; as[r*65+jq+1]=a.y; as[r*65+jq+2]=a.z; as[r*65+jq+3]=a.w;
    }
    for (int m = 0; m < 4; ++m) {
      int idx = m*256 + tid;
      int j = idx >> 4, qq = idx & 15;
      if (qq < 14) {
        float4 v;
        if (qq < 8) v = *(const float4*)(proj + (size_t)(nL + jb + j)*POUT_ + 768 + h*32 + qq*4);
        else        v = *(const float4*)(vpg  + (size_t)(nL + jb + j)*288  + h*24 + (qq-8)*4);
        float* d = bs + j*60 + qq*4;
        d[0]=v.x; d[1]=v.y; d[2]=v.z; d[3]=v.w;
      }
    }
    __syncthreads();
    #pragma unroll 2
    for (int k2 = 0; k2 < 64; ++k2) {
      float av[4];
      #pragma unroll
      for (int d = 0; d < 4; ++d) av[d] = as[(i0+d)*65 + k2];
      float4 bv = *(const float4*)(bs + k2*60 + c0);
      #pragma unroll
      for (int a2 = 0; a2 < 4; ++a2) {
        acc[a2][0] += av[a2]*bv.x; acc[a2][1] += av[a2]*bv.y;
        acc[a2][2] += av[a2]*bv.z; acc[a2][3] += av[a2]*bv.w;
      }
    }
    __syncthreads();
  }
  if (c0 < 32) {
    #pragma unroll
    for (int a2 = 0; a2 < 4; ++a2)
      *(float4*)(feat + (size_t)(nL + ib + i0 + a2)*FEAT_ + 768 + h*32 + c0) =
          make_float4(acc[a2][0], acc[a2][1], acc[a2][2], acc[a2][3]);
  } else if (c0 < 56) {
    #pragma unroll
    for (int a2 = 0; a2 < 4; ++a2)
      *(float4*)(aggr + (size_t)(nL + ib + i0 + a2)*288 + h*24 + (c0-32)) =
          make_float4(acc[a2][0], acc[a2][1], acc[a2][2], acc[a2][3]);
  }
}

// ---------------------------------------------------------------------------
// K9: per-token point post-process: local frame, dist, dir
// ---------------------------------------------------------------------------
__global__ __launch_bounds__(128) void k_post(
    const float* __restrict__ R, const float* __restrict__ coord,
    const float* __restrict__ aggr, float* __restrict__ feat)
{
  const int t = blockIdx.x, tid = threadIdx.x;
  if (tid >= 96) return;
  const float* Rm = R + (size_t)t*9;
  const float cx = coord[(size_t)t*3], cy = coord[(size_t)t*3+1], cz = coord[(size_t)t*3+2];
  const float* ag = aggr + (size_t)t*288;
  float* fb = feat + (size_t)t*FEAT_;
  float dx = ag[tid*3] - cx, dy = ag[tid*3+1] - cy, dz = ag[tid*3+2] - cz;
  float fx = Rm[0]*dx + Rm[3]*dy + Rm[6]*dz;
  float fy = Rm[1]*dx + Rm[4]*dy + Rm[7]*dz;
  float fz = Rm[2]*dx + Rm[5]*dy + Rm[8]*dz;
  float dist = sqrtf(fx*fx + fy*fy + fz*fz);
  float idn = 1.f/(dist + 1e-4f);
  fb[1152+tid*3]=fx; fb[1152+tid*3+1]=fy; fb[1152+tid*3+2]=fz;
  fb[1440+tid]=dist;
  fb[1536+tid*3]=fx*idn; fb[1536+tid*3+1]=fy*idn; fb[1536+tid*3+2]=fz*idn;
}

// ---------------------------------------------------------------------------
// K10: y = feat @ Wout^T.  8 tokens x 64 outputs per block.
// ---------------------------------------------------------------------------
__global__ __launch_bounds__(256) void k_y_gemm(
    const float* __restrict__ feat, const float* __restrict__ Wout,
    float* __restrict__ ybuf)
{
  const int rb = blockIdx.x * 8;
  const int ob = blockIdx.y * 64;
  const int tid = threadIdx.x;
  __shared__ float wt[96*65];   // [k][out], padded
  __shared__ float ft[96*10];   // [k][tok], padded
  const int o = tid & 63, tg = tid >> 6;     // tokens tg*2, tg*2+1
  float acc0 = 0.f, acc1 = 0.f;
  for (int kb = 0; kb < FEAT_; kb += 96) {
    for (int m = 0; m < 6; ++m) {
      int idx = m*256 + tid;
      int r = idx / 24, cq = (idx % 24) * 4;
      float4 v = *(const float4*)(Wout + (size_t)(ob + r)*FEAT_ + kb + cq);
      wt[(cq  )*65 + r] = v.x;
      wt[(cq+1)*65 + r] = v.y;
      wt[(cq+2)*65 + r] = v.z;
      wt[(cq+3)*65 + r] = v.w;
    }
    if (tid < 192) {
      int t = tid / 24, cq = (tid % 24) * 4;
      float4 v = *(const float4*)(feat + (size_t)(rb + t)*FEAT_ + kb + cq);
      ft[(cq  )*10 + t] = v.x;
      ft[(cq+1)*10 + t] = v.y;
      ft[(cq+2)*10 + t] = v.z;
      ft[(cq+3)*10 + t] = v.w;
    }
    __syncthreads();
    #pragma unroll 4
    for (int k2 = 0; k2 < 96; ++k2) {
      float wv = wt[k2*65 + o];
      float2 fv = *(const float2*)(ft + k2*10 + tg*2);
      acc0 += wv * fv.x;
      acc1 += wv * fv.y;
    }
    __syncthreads();
  }
  ybuf[(size_t)(rb + tg*2    )*RD_ + ob + o] = acc0;
  ybuf[(size_t)(rb + tg*2 + 1)*RD_ + ob + o] = acc1;
}

// ---------------------------------------------------------------------------
// K11: per token: bias/mask/residual + LN1 + MLP + LN2
// ---------------------------------------------------------------------------
__device__ __forceinline__ float bsum128(float v, float* red, int tid) {
  #pragma unroll
  for (int off = 1; off < 64; off <<= 1) v += __shfl_xor(v, off, 64);
  __syncthreads();
  if ((tid & 63) == 0) red[tid >> 6] = v;
  __syncthreads();
  return red[0] + red[1];
}

__global__ __launch_bounds__(128) void k_mlp(
    const float* __restrict__ resf, const int* __restrict__ mask,
    const float* __restrict__ ybuf, const float* __restrict__ bout,
    const float* __restrict__ Wm1, const float* __restrict__ bm1,
    const float* __restrict__ Wm2, const float* __restrict__ bm2,
    const float* __restrict__ Wm3, const float* __restrict__ bm3,
    const float* __restrict__ g1, const float* __restrict__ b1,
    const float* __restrict__ g2, const float* __restrict__ b2,
    float* __restrict__ out)
{
  const int t = blockIdx.x, tid = threadIdx.x;
  __shared__ float xb[RD_], h1b[RD_], h2b[RD_];
  __shared__ float red[2];
  float acc = ybuf[(size_t)t*RD_ + tid] + bout[tid];
  if (mask[t] == 0) acc = 0.f;
  float r = resf[(size_t)t*RD_ + tid] + acc;

  float mean = bsum128(r, red, tid) * (1.f/RD_);
  float d = r - mean;
  float var = bsum128(d*d, red, tid) * (1.f/RD_);
  float xn = d * rsqrtf(var + 1e-5f) * g1[tid] + b1[tid];
  xb[tid] = xn;
  __syncthreads();

  float a1 = bm1[tid];
  {
    const float4* w4 = (const float4*)(Wm1 + (size_t)tid*RD_);
    #pragma unroll
    for (int c = 0; c < RD_/4; ++c) { float4 a = w4[c]; a1 += a.x*xb[4*c]+a.y*xb[4*c+1]+a.z*xb[4*c+2]+a.w*xb[4*c+3]; }
  }
  a1 = fmaxf(a1, 0.f);
  h1b[tid] = a1;
  __syncthreads();

  float a2 = bm2[tid];
  {
    const float4* w4 = (const float4*)(Wm2 + (size_t)tid*RD_);
    #pragma unroll
    for (int c = 0; c < RD_/4; ++c) { float4 a = w4[c]; a2 += a.x*h1b[4*c]+a.y*h1b[4*c+1]+a.z*h1b[4*c+2]+a.w*h1b[4*c+3]; }
  }
  a2 = fmaxf(a2, 0.f);
  h2b[tid] = a2;
  __syncthreads();

  float a3 = bm3[tid];
  {
    const float4* w4 = (const float4*)(Wm3 + (size_t)tid*RD_);
    #pragma unroll
    for (int c = 0; c < RD_/4; ++c) { float4 a = w4[c]; a3 += a.x*h2b[4*c]+a.y*h2b[4*c+1]+a.z*h2b[4*c+2]+a.w*h2b[4*c+3]; }
  }
  float r2 = xn + a3;
  float mean2 = bsum128(r2, red, tid) * (1.f/RD_);
  float d2 = r2 - mean2;
  float var2 = bsum128(d2*d2, red, tid) * (1.f/RD_);
  out[(size_t)t*RD_ + tid] = d2 * rsqrtf(var2 + 1e-5f) * g2[tid] + b2[tid];
}

// ---------------------------------------------------------------------------
extern "C" void kernel_launch(void* const* d_in, const int* in_sizes, int n_in,
                              void* d_out, int out_size, void* d_ws, size_t ws_size,
                              hipStream_t stream) {
  (void)in_sizes; (void)n_in; (void)out_size; (void)ws_size;
  const float* R     = (const float*)d_in[0];
  const float* coord = (const float*)d_in[1];
  const float* resf  = (const float*)d_in[2];
  const float* pair  = (const float*)d_in[3];
  const int*   mask  = (const int*)  d_in[4];
  const float* Wq    = (const float*)d_in[5];
  const float* Wk    = (const float*)d_in[6];
  const float* Wv    = (const float*)d_in[7];
  const float* Wpb   = (const float*)d_in[8];
  const float* spc   = (const float*)d_in[9];
  const float* Wqp   = (const float*)d_in[10];
  const float* Wkp   = (const float*)d_in[11];
  const float* Wvp   = (const float*)d_in[12];
  const float* Wout  = (const float*)d_in[13];
  const float* bout  = (const float*)d_in[14];
  const float* Wm1   = (const float*)d_in[15];
  const float* bm1   = (const float*)d_in[16];
  const float* Wm2   = (const float*)d_in[17];
  const float* bm2   = (const float*)d_in[18];
  const float* Wm3   = (const float*)d_in[19];
  const float* bm3   = (const float*)d_in[20];
  const float* g1    = (const float*)d_in[21];
  const float* b1    = (const float*)d_in[22];
  const float* g2    = (const float*)d_in[23];
  const float* b2    = (const float*)d_in[24];

  float* ws   = (float*)d_ws;
  float* proj = ws;                               // NL*2016
  float* qt   = proj + (size_t)NL_*POUT_;         // 24*512*64  (dead after k_lgns)
  float* kt   = qt   + (size_t)N_*H_*L_*64;       // 24*512*64  (dead after k_lgns)
  float* vpg  = kt   + (size_t)N_*H_*L_*64;       // NL*288
  float* lgal = vpg  + (size_t)NL_*288;           // 24*512*512 (logits -> alpha)
  float* feat = lgal + (size_t)N_*H_*L_*L_;       // NL*1824
  float* ybuf = feat + (size_t)NL_*FEAT_;         // NL*128
  float* aggr = ybuf + (size_t)NL_*RD_;           // NL*288
  float* part = qt;                               // NL*2*768 == qt+kt exactly

  k_proj_gemm<<<dim3(NL_/8, 16), 256, 0, stream>>>(resf, Wq, Wk, Wv, Wqp, Wkp, Wvp, proj);
  k_rot<<<NL_, 64, 0, stream>>>(R, coord, spc, proj, qt, kt, vpg);
  k_lgns<<<dim3(L_/64, L_/64, N_*H_), 256, 0, stream>>>(qt, kt, lgal);
  k_pbias<<<dim3(L_/64, L_, N_), 256, 0, stream>>>(pair, mask, Wpb, lgal);
  k_softx<<<(N_*H_*L_)/4, 256, 0, stream>>>(mask, lgal);
  k_paggr<<<dim3(2, L_, N_), 256, 0, stream>>>(pair, lgal, part);
  k_pred<<<NL_, 256, 0, stream>>>(part, feat);
  k_av<<<dim3(L_/64, N_*H_), 256, 0, stream>>>(lgal, proj, vpg, feat, aggr);
  k_post<<<NL_, 128, 0, stream>>>(R, coord, aggr, feat);
  k_y_gemm<<<dim3(NL_/8, 2), 256, 0, stream>>>(feat, Wout, ybuf);
  k_mlp<<<NL_, 128, 0, stream>>>(resf, mask, ybuf, bout, Wm1, bm1, Wm2, bm2, Wm3, bm3,
                                 g1, b1, g2, b2, (float*)d_out);
}

// Round 6
// 319.891 us; speedup vs baseline: 1.0352x; 1.0352x over previous
//
#include <hip/hip_runtime.h>
#include <hip/hip_bf16.h>

#define N_ 2
#define L_ 512
#define RD_ 128
#define PD_ 64
#define H_ 12
#define NL_ (N_*L_)
#define POUT_ 2016          /* 3*384 + 3*288 */
#define FEAT_ 1824
#define INF_ 100000.0f
#define ISQD_ 0.17677669529663687f   /* 1/sqrt(32) */
#define ISQ3_ 0.5773502691896258f    /* sqrt(1/3) */
#define LL_ ((size_t)L_*L_)

// ---------------------------------------------------------------------------
// K1: projection GEMM. proj[token][2016] = resf @ [Wq|Wk|Wv|Wqp|Wkp|Wvp]^T
// ---------------------------------------------------------------------------
__global__ __launch_bounds__(256) void k_proj_gemm(
    const float* __restrict__ resf,
    const float* __restrict__ Wq, const float* __restrict__ Wk, const float* __restrict__ Wv,
    const float* __restrict__ Wqp, const float* __restrict__ Wkp, const float* __restrict__ Wvp,
    float* __restrict__ proj)
{
  const int rb = blockIdx.x * 8;
  const int ob = blockIdx.y * 128;
  const int tid = threadIdx.x;
  __shared__ float xt[8*132];
  __shared__ float wt[128*132];
  {
    int r = tid >> 5, kq = (tid & 31) * 4;
    float4 v = *(const float4*)(resf + (size_t)(rb + r)*RD_ + kq);
    xt[r*132+kq]=v.x; xt[r*132+kq+1]=v.y; xt[r*132+kq+2]=v.z; xt[r*132+kq+3]=v.w;
  }
  for (int m = 0; m < 16; ++m) {
    int idx = m*256 + tid;
    int r = idx >> 5, kq = (idx & 31) * 4;
    int o = ob + r;
    float4 v;
    if (o < 384)        v = *(const float4*)(Wq  + (size_t)o*RD_ + kq);
    else if (o < 768)   v = *(const float4*)(Wk  + (size_t)(o-384)*RD_ + kq);
    else if (o < 1152)  v = *(const float4*)(Wv  + (size_t)(o-768)*RD_ + kq);
    else if (o < 1440)  v = *(const float4*)(Wqp + (size_t)(o-1152)*RD_ + kq);
    else if (o < 1728)  v = *(const float4*)(Wkp + (size_t)(o-1440)*RD_ + kq);
    else if (o < POUT_) v = *(const float4*)(Wvp + (size_t)(o-1728)*RD_ + kq);
    else                v = make_float4(0.f,0.f,0.f,0.f);
    wt[r*132+kq]=v.x; wt[r*132+kq+1]=v.y; wt[r*132+kq+2]=v.z; wt[r*132+kq+3]=v.w;
  }
  __syncthreads();
  const int tt = tid & 7, g = tid >> 3;
  float acc0=0.f, acc1=0.f, acc2=0.f, acc3=0.f;
  #pragma unroll 4
  for (int k2 = 0; k2 < RD_; ++k2) {
    float xv = xt[tt*132 + k2];
    acc0 += xv * wt[(g     )*132 + k2];
    acc1 += xv * wt[(g + 32)*132 + k2];
    acc2 += xv * wt[(g + 64)*132 + k2];
    acc3 += xv * wt[(g + 96)*132 + k2];
  }
  float* dst = proj + (size_t)(rb + tt)*POUT_ + ob;
  if (ob + g      < POUT_) dst[g]      = acc0;
  if (ob + g + 32 < POUT_) dst[g+32]   = acc1;
  if (ob + g + 64 < POUT_) dst[g+64]   = acc2;
  if (ob + g + 96 < POUT_) dst[g+96]   = acc3;
}

// ---------------------------------------------------------------------------
// K2: per-token rotate + build Q~/K~ (58-dim augmented, padded to 64)
// ---------------------------------------------------------------------------
__global__ __launch_bounds__(64) void k_rot(
    const float* __restrict__ R, const float* __restrict__ coord,
    const float* __restrict__ spc, const float* __restrict__ proj,
    float* __restrict__ qt, float* __restrict__ kt, float* __restrict__ vpg)
{
  const int t = blockIdx.x;
  const int n = t / L_, i = t % L_;
  const int tid = threadIdx.x;
  __shared__ float prow[POUT_];
  __shared__ float qpl[288], kpl[288], vpl[288];
  __shared__ float qqs[H_], kks[H_], coefs[H_];
  for (int m = tid; m < POUT_/4; m += 64)
    ((float4*)prow)[m] = *((const float4*)(proj + (size_t)t*POUT_) + m);
  if (tid < H_) coefs[tid] = -log1pf(expf(spc[tid])) * (1.0f/12.0f);
  __syncthreads();
  const float* Rm = R + (size_t)t*9;
  const float r00=Rm[0],r01=Rm[1],r02=Rm[2],r10=Rm[3],r11=Rm[4],r12=Rm[5],r20=Rm[6],r21=Rm[7],r22=Rm[8];
  const float cx = coord[(size_t)t*3], cy = coord[(size_t)t*3+1], cz = coord[(size_t)t*3+2];
  for (int idx = tid; idx < 288; idx += 64) {
    int mat = idx / 96, p = idx % 96;
    const float* s = prow + 1152 + mat*288 + p*3;
    float px=s[0], py=s[1], pz=s[2];
    float gx = r00*px + r01*py + r02*pz + cx;
    float gy = r10*px + r11*py + r12*pz + cy;
    float gz = r20*px + r21*py + r22*pz + cz;
    float* d = (mat==0? qpl : mat==1? kpl : vpl) + p*3;
    d[0]=gx; d[1]=gy; d[2]=gz;
  }
  __syncthreads();
  if (tid < 24) {
    int mat = tid / H_, h = tid % H_;
    const float* s = (mat==0? qpl : kpl) + h*24;
    float acc = 0.f;
    #pragma unroll
    for (int c2 = 0; c2 < 24; ++c2) acc += s[c2]*s[c2];
    (mat==0? qqs : kks)[h] = acc;
  }
  for (int m = tid; m < 72; m += 64)
    ((float4*)(vpg + (size_t)t*288))[m] = ((float4*)vpl)[m];
  __syncthreads();
  for (int idx = tid; idx < 2*H_*64; idx += 64) {
    int which = idx / 768, rem = idx % 768, h = rem >> 6, c = rem & 63;
    float val;
    if (which == 0) {
      if (c < 32)       val = prow[h*32 + c] * ISQD_;
      else if (c < 56)  val = qpl[h*24 + (c-32)] * (-2.0f * coefs[h]);
      else if (c == 56) val = coefs[h] * qqs[h];
      else if (c == 57) val = coefs[h];
      else              val = 0.f;
      qt[((size_t)(n*H_ + h)*L_ + i)*64 + c] = val;
    } else {
      if (c < 32)       val = prow[384 + h*32 + c];
      else if (c < 56)  val = kpl[h*24 + (c-32)];
      else if (c == 56) val = 1.0f;
      else if (c == 57) val = kks[h];
      else              val = 0.f;
      kt[((size_t)(n*H_ + h)*L_ + i)*64 + c] = val;
    }
  }
}

// ---------------------------------------------------------------------------
// K3: logits GEMM (node+spatial): lgal[n][h][i][j] = Qt[i] . Kt[j]  (raw)
// ---------------------------------------------------------------------------
__global__ __launch_bounds__(256) void k_lgns(
    const float* __restrict__ qt, const float* __restrict__ kt,
    float* __restrict__ lgal)
{
  const int jb = blockIdx.x * 64, ib = blockIdx.y * 64, nh = blockIdx.z;
  const int tid = threadIdx.x;
  __shared__ float qs[64*65], ks[64*65];
  for (int m = 0; m < 4; ++m) {
    int idx = m*256 + tid;
    int r = idx >> 4, kq = (idx & 15) * 4;
    float4 a = *(const float4*)(qt + ((size_t)nh*L_ + ib + r)*64 + kq);
    qs[r*65+kq]=a.x; qs[r*65+kq+1]=a.y; qs[r*65+kq+2]=a.z; qs[r*65+kq+3]=a.w;
    float4 b = *(const float4*)(kt + ((size_t)nh*L_ + jb + r)*64 + kq);
    ks[r*65+kq]=b.x; ks[r*65+kq+1]=b.y; ks[r*65+kq+2]=b.z; ks[r*65+kq+3]=b.w;
  }
  __syncthreads();
  const int tx = tid & 15, ty = tid >> 4;
  const int i0 = ty*4, j0 = tx*4;
  float acc[4][4] = {};
  #pragma unroll 2
  for (int k2 = 0; k2 < 64; ++k2) {
    float qv[4], kv[4];
    #pragma unroll
    for (int d = 0; d < 4; ++d) { qv[d] = qs[(i0+d)*65 + k2]; kv[d] = ks[(j0+d)*65 + k2]; }
    #pragma unroll
    for (int a2 = 0; a2 < 4; ++a2)
      #pragma unroll
      for (int b2 = 0; b2 < 4; ++b2) acc[a2][b2] += qv[a2]*kv[b2];
  }
  #pragma unroll
  for (int a2 = 0; a2 < 4; ++a2) {
    float4 v = make_float4(acc[a2][0], acc[a2][1], acc[a2][2], acc[a2][3]);
    *(float4*)(lgal + ((size_t)nh*L_ + ib + i0 + a2)*L_ + jb + j0) = v;
  }
}

// ---------------------------------------------------------------------------
// K4: pair bias + mask + scale (RMW lgal). Block = (jt2 128j, i, n).
// Two 64-j tiles with register ping-pong staging to hide HBM latency.
// lane = j-row (stride-67 = conflict-free), wave = head-triple {w,w+4,w+8}.
// ---------------------------------------------------------------------------
__global__ __launch_bounds__(256) void k_pbias(
    const float* __restrict__ pair, const int* __restrict__ mask,
    const float* __restrict__ Wpb, float* __restrict__ lgal)
{
  const int jt2 = blockIdx.x, i = blockIdx.y, n = blockIdx.z;
  const int bi = n*L_ + i;
  const int tid = threadIdx.x;
  __shared__ float pt[2][64*67];
  const int sr = tid >> 4, scq = (tid & 15)*4;
  // stage tile 0
  #pragma unroll
  for (int m = 0; m < 4; ++m) {
    int r = m*16 + sr;
    float4 v = *(const float4*)(pair + ((size_t)bi*L_ + jt2*128 + r)*PD_ + scq);
    float* d = pt[0] + r*67 + scq;
    d[0]=v.x; d[1]=v.y; d[2]=v.z; d[3]=v.w;
  }
  __syncthreads();
  // issue tile-1 loads into registers (overlaps tile-0 compute)
  float4 rg[4];
  #pragma unroll
  for (int m = 0; m < 4; ++m) {
    int r = m*16 + sr;
    rg[m] = *(const float4*)(pair + ((size_t)bi*L_ + jt2*128 + 64 + r)*PD_ + scq);
  }

  const int r = tid & 63;
  const int w = __builtin_amdgcn_readfirstlane(tid >> 6);
  const float* w0 = Wpb + (w    )*64;
  const float* w1 = Wpb + (w + 4)*64;
  const float* w2 = Wpb + (w + 8)*64;
  const int mi = mask[bi];

  // ---- compute tile 0 ----
  {
    const int j = jt2*128 + r;
    const float* pr = pt[0] + r*67;
    float a0=0.f, a1=0.f, a2=0.f;
    #pragma unroll 16
    for (int c = 0; c < 64; ++c) {
      float pv = pr[c];
      a0 += pv*w0[c]; a1 += pv*w1[c]; a2 += pv*w2[c];
    }
    const float mt = (mi && mask[n*L_ + j]) ? 0.f : -INF_;
    size_t base = ((size_t)(n*H_ + w)*L_ + i)*L_ + j;
    float l0 = lgal[base], l1 = lgal[base + 4*LL_], l2 = lgal[base + 8*LL_];
    lgal[base        ] = (l0 + a0)*ISQ3_ + mt;
    lgal[base + 4*LL_] = (l1 + a1)*ISQ3_ + mt;
    lgal[base + 8*LL_] = (l2 + a2)*ISQ3_ + mt;
  }

  // write tile-1 regs to LDS, then compute
  #pragma unroll
  for (int m = 0; m < 4; ++m) {
    int rr = m*16 + sr;
    float* d = pt[1] + rr*67 + scq;
    d[0]=rg[m].x; d[1]=rg[m].y; d[2]=rg[m].z; d[3]=rg[m].w;
  }
  __syncthreads();
  {
    const int j = jt2*128 + 64 + r;
    const float* pr = pt[1] + r*67;
    float a0=0.f, a1=0.f, a2=0.f;
    #pragma unroll 16
    for (int c = 0; c < 64; ++c) {
      float pv = pr[c];
      a0 += pv*w0[c]; a1 += pv*w1[c]; a2 += pv*w2[c];
    }
    const float mt = (mi && mask[n*L_ + j]) ? 0.f : -INF_;
    size_t base = ((size_t)(n*H_ + w)*L_ + i)*L_ + j;
    float l0 = lgal[base], l1 = lgal[base + 4*LL_], l2 = lgal[base + 8*LL_];
    lgal[base        ] = (l0 + a0)*ISQ3_ + mt;
    lgal[base + 4*LL_] = (l1 + a1)*ISQ3_ + mt;
    lgal[base + 8*LL_] = (l2 + a2)*ISQ3_ + mt;
  }
}

// ---------------------------------------------------------------------------
// K5: softmax per (n,h,i) row, one wave per row, row held in registers.
// ---------------------------------------------------------------------------
__global__ __launch_bounds__(256) void k_softx(
    const int* __restrict__ mask, float* __restrict__ lgal)
{
  const int tid = threadIdx.x;
  const int wid = tid >> 6, lane = tid & 63;
  const int rid = blockIdx.x*4 + wid;          // (n*H+h)*L + i
  const int i = rid & (L_-1);
  const int nh = rid >> 9;
  const int n = nh / H_;
  float4* r4 = (float4*)(lgal + (size_t)rid * L_);
  float4 p0 = r4[lane], p1 = r4[lane + 64];
  float mx = fmaxf(fmaxf(fmaxf(p0.x,p0.y),fmaxf(p0.z,p0.w)),
                   fmaxf(fmaxf(p1.x,p1.y),fmaxf(p1.z,p1.w)));
  #pragma unroll
  for (int off = 1; off < 64; off <<= 1) mx = fmaxf(mx, __shfl_xor(mx, off, 64));
  p0.x = expf(p0.x - mx); p0.y = expf(p0.y - mx);
  p0.z = expf(p0.z - mx); p0.w = expf(p0.w - mx);
  p1.x = expf(p1.x - mx); p1.y = expf(p1.y - mx);
  p1.z = expf(p1.z - mx); p1.w = expf(p1.w - mx);
  float s = p0.x+p0.y+p0.z+p0.w + p1.x+p1.y+p1.z+p1.w;
  #pragma unroll
  for (int off = 1; off < 64; off <<= 1) s += __shfl_xor(s, off, 64);
  const float inv = (mask[n*L_ + i] ? 1.f : 0.f) / s;
  p0.x*=inv; p0.y*=inv; p0.z*=inv; p0.w*=inv;
  p1.x*=inv; p1.y*=inv; p1.z*=inv; p1.w*=inv;
  r4[lane] = p0; r4[lane + 64] = p1;
}

// ---------------------------------------------------------------------------
// K6: feat_pair. Block = (i, n), 4 waves, NO LDS / NO barriers.
// lane = c (coalesced 256B row loads, L1-shared across waves);
// wave = head-triple; alpha rows wave-uniform -> s_load.
// ---------------------------------------------------------------------------
__global__ __launch_bounds__(256) void k_paggr(
    const float* __restrict__ pair, const float* __restrict__ lgal,
    float* __restrict__ feat)
{
  const int i = blockIdx.x, n = blockIdx.y;
  const int bi = n*L_ + i;
  const int lane = threadIdx.x & 63;
  const int w = __builtin_amdgcn_readfirstlane(threadIdx.x >> 6);
  const float* a0 = lgal + ((size_t)(n*H_ + w    )*L_ + i)*L_;
  const float* a1 = lgal + ((size_t)(n*H_ + w + 4)*L_ + i)*L_;
  const float* a2 = lgal + ((size_t)(n*H_ + w + 8)*L_ + i)*L_;
  const float* pb = pair + (size_t)bi*L_*PD_ + lane;
  float acc0=0.f, acc1=0.f, acc2=0.f;
  #pragma unroll 8
  for (int j = 0; j < L_; ++j) {
    float pv = pb[(size_t)j*PD_];
    acc0 += pv * a0[j];
    acc1 += pv * a1[j];
    acc2 += pv * a2[j];
  }
  float* fb = feat + (size_t)bi*FEAT_;
  fb[(w    )*64 + lane] = acc0;
  fb[(w + 4)*64 + lane] = acc1;
  fb[(w + 8)*64 + lane] = acc2;
}

// ---------------------------------------------------------------------------
// K7: per (n,h,z) GEMM partials: C[i, 0:56] = alpha[i, z*256+j] @ [v|vp]
// pav[z][nh][i][56]
// ---------------------------------------------------------------------------
__global__ __launch_bounds__(256) void k_av(
    const float* __restrict__ lgal, const float* __restrict__ proj,
    const float* __restrict__ vpg, float* __restrict__ pav)
{
  const int ib = blockIdx.x * 64;
  const int nh = blockIdx.y;
  const int z  = blockIdx.z;
  const int n = nh / H_, h = nh % H_, nL = n*L_;
  const int tid = threadIdx.x;
  __shared__ float as[64*65];
  __shared__ float bs[64*60];
  const int tx = tid & 15, ty = tid >> 4;
  const int i0 = ty*4, c0 = tx*4;
  float acc[4][4] = {};
  for (int jb = z*256; jb < z*256 + 256; jb += 64) {
    for (int m = 0; m < 4; ++m) {
      int idx = m*256 + tid;
      int r = idx >> 4, jq = (idx & 15) * 4;
      float4 a = *(const float4*)(lgal + ((size_t)nh*L_ + ib + r)*L_ + jb + jq);
      as[r*65+jq]=a.x; as[r*65+jq+1]=a.y; as[r*65+jq+2]=a.z; as[r*65+jq+3]=a.w;
    }
    for (int m = 0; m < 4; ++m) {
      int idx = m*256 + tid;
      int j = idx >> 4, qq = idx & 15;
      if (qq < 14) {
        float4 v;
        if (qq < 8) v = *(const float4*)(proj + (size_t)(nL + jb + j)*POUT_ + 768 + h*32 + qq*4);
        else        v = *(const float4*)(vpg  + (size_t)(nL + jb + j)*288  + h*24 + (qq-8)*4);
        float* d = bs + j*60 + qq*4;
        d[0]=v.x; d[1]=v.y; d[2]=v.z; d[3]=v.w;
      }
    }
    __syncthreads();
    #pragma unroll 2
    for (int k2 = 0; k2 < 64; ++k2) {
      float av[4];
      #pragma unroll
      for (int d = 0; d < 4; ++d) av[d] = as[(i0+d)*65 + k2];
      float4 bv = *(const float4*)(bs + k2*60 + c0);
      #pragma unroll
      for (int a2 = 0; a2 < 4; ++a2) {
        acc[a2][0] += av[a2]*bv.x; acc[a2][1] += av[a2]*bv.y;
        acc[a2][2] += av[a2]*bv.z; acc[a2][3] += av[a2]*bv.w;
      }
    }
    __syncthreads();
  }
  if (c0 < 56) {
    #pragma unroll
    for (int a2 = 0; a2 < 4; ++a2)
      *(float4*)(pav + (((size_t)z*24 + nh)*L_ + ib + i0 + a2)*56 + c0) =
          make_float4(acc[a2][0], acc[a2][1], acc[a2][2], acc[a2][3]);
  }
}

// ---------------------------------------------------------------------------
// K8: reduce k_av partials -> feat_node + aggr
// ---------------------------------------------------------------------------
__global__ __launch_bounds__(256) void k_avred(
    const float* __restrict__ pav, float* __restrict__ feat,
    float* __restrict__ aggr)
{
  const int tok = blockIdx.x, tid = threadIdx.x;
  const int n = tok / L_, i = tok % L_;
  float* fb = feat + (size_t)tok*FEAT_;
  float* ag = aggr + (size_t)tok*288;
  for (int u = tid; u < 672; u += 256) {
    int h = u / 56, c = u % 56;
    size_t off = (((size_t)(n*H_ + h))*L_ + i)*56 + c;
    float v = pav[off] + pav[off + (size_t)24*L_*56];
    if (c < 32) fb[768 + h*32 + c] = v;
    else        ag[h*24 + (c - 32)] = v;
  }
}

// ---------------------------------------------------------------------------
// K9: per-token point post-process: local frame, dist, dir
// ---------------------------------------------------------------------------
__global__ __launch_bounds__(128) void k_post(
    const float* __restrict__ R, const float* __restrict__ coord,
    const float* __restrict__ aggr, float* __restrict__ feat)
{
  const int t = blockIdx.x, tid = threadIdx.x;
  if (tid >= 96) return;
  const float* Rm = R + (size_t)t*9;
  const float cx = coord[(size_t)t*3], cy = coord[(size_t)t*3+1], cz = coord[(size_t)t*3+2];
  const float* ag = aggr + (size_t)t*288;
  float* fb = feat + (size_t)t*FEAT_;
  float dx = ag[tid*3] - cx, dy = ag[tid*3+1] - cy, dz = ag[tid*3+2] - cz;
  float fx = Rm[0]*dx + Rm[3]*dy + Rm[6]*dz;
  float fy = Rm[1]*dx + Rm[4]*dy + Rm[7]*dz;
  float fz = Rm[2]*dx + Rm[5]*dy + Rm[8]*dz;
  float dist = sqrtf(fx*fx + fy*fy + fz*fz);
  float idn = 1.f/(dist + 1e-4f);
  fb[1152+tid*3]=fx; fb[1152+tid*3+1]=fy; fb[1152+tid*3+2]=fz;
  fb[1440+tid]=dist;
  fb[1536+tid*3]=fx*idn; fb[1536+tid*3+1]=fy*idn; fb[1536+tid*3+2]=fz*idn;
}

// ---------------------------------------------------------------------------
// K10: y = feat @ Wout^T.  8 tokens x 64 outputs per block.
// ---------------------------------------------------------------------------
__global__ __launch_bounds__(256) void k_y_gemm(
    const float* __restrict__ feat, const float* __restrict__ Wout,
    float* __restrict__ ybuf)
{
  const int rb = blockIdx.x * 8;
  const int ob = blockIdx.y * 64;
  const int tid = threadIdx.x;
  __shared__ float wt[96*65];   // [k][out], padded
  __shared__ float ft[96*10];   // [k][tok], padded
  const int o = tid & 63, tg = tid >> 6;     // tokens tg*2, tg*2+1
  float acc0 = 0.f, acc1 = 0.f;
  for (int kb = 0; kb < FEAT_; kb += 96) {
    for (int m = 0; m < 6; ++m) {
      int idx = m*256 + tid;
      int r = idx / 24, cq = (idx % 24) * 4;
      float4 v = *(const float4*)(Wout + (size_t)(ob + r)*FEAT_ + kb + cq);
      wt[(cq  )*65 + r] = v.x;
      wt[(cq+1)*65 + r] = v.y;
      wt[(cq+2)*65 + r] = v.z;
      wt[(cq+3)*65 + r] = v.w;
    }
    if (tid < 192) {
      int t = tid / 24, cq = (tid % 24) * 4;
      float4 v = *(const float4*)(feat + (size_t)(rb + t)*FEAT_ + kb + cq);
      ft[(cq  )*10 + t] = v.x;
      ft[(cq+1)*10 + t] = v.y;
      ft[(cq+2)*10 + t] = v.z;
      ft[(cq+3)*10 + t] = v.w;
    }
    __syncthreads();
    #pragma unroll 4
    for (int k2 = 0; k2 < 96; ++k2) {
      float wv = wt[k2*65 + o];
      float2 fv = *(const float2*)(ft + k2*10 + tg*2);
      acc0 += wv * fv.x;
      acc1 += wv * fv.y;
    }
    __syncthreads();
  }
  ybuf[(size_t)(rb + tg*2    )*RD_ + ob + o] = acc0;
  ybuf[(size_t)(rb + tg*2 + 1)*RD_ + ob + o] = acc1;
}

// ---------------------------------------------------------------------------
// K11: per token: bias/mask/residual + LN1 + MLP + LN2
// ---------------------------------------------------------------------------
__device__ __forceinline__ float bsum128(float v, float* red, int tid) {
  #pragma unroll
  for (int off = 1; off < 64; off <<= 1) v += __shfl_xor(v, off, 64);
  __syncthreads();
  if ((tid & 63) == 0) red[tid >> 6] = v;
  __syncthreads();
  return red[0] + red[1];
}

__global__ __launch_bounds__(128) void k_mlp(
    const float* __restrict__ resf, const int* __restrict__ mask,
    const float* __restrict__ ybuf, const float* __restrict__ bout,
    const float* __restrict__ Wm1, const float* __restrict__ bm1,
    const float* __restrict__ Wm2, const float* __restrict__ bm2,
    const float* __restrict__ Wm3, const float* __restrict__ bm3,
    const float* __restrict__ g1, const float* __restrict__ b1,
    const float* __restrict__ g2, const float* __restrict__ b2,
    float* __restrict__ out)
{
  const int t = blockIdx.x, tid = threadIdx.x;
  __shared__ float xb[RD_], h1b[RD_], h2b[RD_];
  __shared__ float red[2];
  float acc = ybuf[(size_t)t*RD_ + tid] + bout[tid];
  if (mask[t] == 0) acc = 0.f;
  float r = resf[(size_t)t*RD_ + tid] + acc;

  float mean = bsum128(r, red, tid) * (1.f/RD_);
  float d = r - mean;
  float var = bsum128(d*d, red, tid) * (1.f/RD_);
  float xn = d * rsqrtf(var + 1e-5f) * g1[tid] + b1[tid];
  xb[tid] = xn;
  __syncthreads();

  float a1 = bm1[tid];
  {
    const float4* w4 = (const float4*)(Wm1 + (size_t)tid*RD_);
    #pragma unroll
    for (int c = 0; c < RD_/4; ++c) { float4 a = w4[c]; a1 += a.x*xb[4*c]+a.y*xb[4*c+1]+a.z*xb[4*c+2]+a.w*xb[4*c+3]; }
  }
  a1 = fmaxf(a1, 0.f);
  h1b[tid] = a1;
  __syncthreads();

  float a2 = bm2[tid];
  {
    const float4* w4 = (const float4*)(Wm2 + (size_t)tid*RD_);
    #pragma unroll
    for (int c = 0; c < RD_/4; ++c) { float4 a = w4[c]; a2 += a.x*h1b[4*c]+a.y*h1b[4*c+1]+a.z*h1b[4*c+2]+a.w*h1b[4*c+3]; }
  }
  a2 = fmaxf(a2, 0.f);
  h2b[tid] = a2;
  __syncthreads();

  float a3 = bm3[tid];
  {
    const float4* w4 = (const float4*)(Wm3 + (size_t)tid*RD_);
    #pragma unroll
    for (int c = 0; c < RD_/4; ++c) { float4 a = w4[c]; a3 += a.x*h2b[4*c]+a.y*h2b[4*c+1]+a.z*h2b[4*c+2]+a.w*h2b[4*c+3]; }
  }
  float r2 = xn + a3;
  float mean2 = bsum128(r2, red, tid) * (1.f/RD_);
  float d2 = r2 - mean2;
  float var2 = bsum128(d2*d2, red, tid) * (1.f/RD_);
  out[(size_t)t*RD_ + tid] = d2 * rsqrtf(var2 + 1e-5f) * g2[tid] + b2[tid];
}

// ---------------------------------------------------------------------------
extern "C" void kernel_launch(void* const* d_in, const int* in_sizes, int n_in,
                              void* d_out, int out_size, void* d_ws, size_t ws_size,
                              hipStream_t stream) {
  (void)in_sizes; (void)n_in; (void)out_size; (void)ws_size;
  const float* R     = (const float*)d_in[0];
  const float* coord = (const float*)d_in[1];
  const float* resf  = (const float*)d_in[2];
  const float* pair  = (const float*)d_in[3];
  const int*   mask  = (const int*)  d_in[4];
  const float* Wq    = (const float*)d_in[5];
  const float* Wk    = (const float*)d_in[6];
  const float* Wv    = (const float*)d_in[7];
  const float* Wpb   = (const float*)d_in[8];
  const float* spc   = (const float*)d_in[9];
  const float* Wqp   = (const float*)d_in[10];
  const float* Wkp   = (const float*)d_in[11];
  const float* Wvp   = (const float*)d_in[12];
  const float* Wout  = (const float*)d_in[13];
  const float* bout  = (const float*)d_in[14];
  const float* Wm1   = (const float*)d_in[15];
  const float* bm1   = (const float*)d_in[16];
  const float* Wm2   = (const float*)d_in[17];
  const float* bm2   = (const float*)d_in[18];
  const float* Wm3   = (const float*)d_in[19];
  const float* bm3   = (const float*)d_in[20];
  const float* g1    = (const float*)d_in[21];
  const float* b1    = (const float*)d_in[22];
  const float* g2    = (const float*)d_in[23];
  const float* b2    = (const float*)d_in[24];

  float* ws   = (float*)d_ws;
  float* proj = ws;                               // NL*2016
  float* qt   = proj + (size_t)NL_*POUT_;         // 24*512*64  (dead after k_lgns)
  float* kt   = qt   + (size_t)N_*H_*L_*64;       // 24*512*64  (dead after k_lgns)
  float* vpg  = kt   + (size_t)N_*H_*L_*64;       // NL*288
  float* lgal = vpg  + (size_t)NL_*288;           // 24*512*512 (logits -> alpha)
  float* feat = lgal + (size_t)N_*H_*L_*L_;       // NL*1824
  float* ybuf = feat + (size_t)NL_*FEAT_;         // NL*128
  float* aggr = ybuf + (size_t)NL_*RD_;           // NL*288
  float* pav  = qt;                               // 2*24*512*56 floats (5.5MB) <= qt+kt

  k_proj_gemm<<<dim3(NL_/8, 16), 256, 0, stream>>>(resf, Wq, Wk, Wv, Wqp, Wkp, Wvp, proj);
  k_rot<<<NL_, 64, 0, stream>>>(R, coord, spc, proj, qt, kt, vpg);
  k_lgns<<<dim3(L_/64, L_/64, N_*H_), 256, 0, stream>>>(qt, kt, lgal);
  k_pbias<<<dim3(L_/128, L_, N_), 256, 0, stream>>>(pair, mask, Wpb, lgal);
  k_softx<<<(N_*H_*L_)/4, 256, 0, stream>>>(mask, lgal);
  k_paggr<<<dim3(L_, N_), 256, 0, stream>>>(pair, lgal, feat);
  k_av<<<dim3(L_/64, N_*H_, 2), 256, 0, stream>>>(lgal, proj, vpg, pav);
  k_avred<<<NL_, 256, 0, stream>>>(pav, feat, aggr);
  k_post<<<NL_, 128, 0, stream>>>(R, coord, aggr, feat);
  k_y_gemm<<<dim3(NL_/8, 2), 256, 0, stream>>>(feat, Wout, ybuf);
  k_mlp<<<NL_, 128, 0, stream>>>(resf, mask, ybuf, bout, Wm1, bm1, Wm2, bm2, Wm3, bm3,
                                 g1, b1, g2, b2, (float*)d_out);
}

// Round 7
// 244.429 us; speedup vs baseline: 1.3548x; 1.3087x over previous
//
#include <hip/hip_runtime.h>
#include <hip/hip_bf16.h>

#define N_ 2
#define L_ 512
#define RD_ 128
#define PD_ 64
#define H_ 12
#define NL_ (N_*L_)
#define POUT_ 2016          /* 3*384 + 3*288 */
#define FEAT_ 1824
#define INF_ 100000.0f
#define ISQD_ 0.17677669529663687f   /* 1/sqrt(32) */
#define ISQ3_ 0.5773502691896258f    /* sqrt(1/3) */
#define LL_ ((size_t)L_*L_)

// ---------------------------------------------------------------------------
// K1: projection GEMM. proj[token][2016] = resf @ [Wq|Wk|Wv|Wqp|Wkp|Wvp]^T
// ---------------------------------------------------------------------------
__global__ __launch_bounds__(256) void k_proj_gemm(
    const float* __restrict__ resf,
    const float* __restrict__ Wq, const float* __restrict__ Wk, const float* __restrict__ Wv,
    const float* __restrict__ Wqp, const float* __restrict__ Wkp, const float* __restrict__ Wvp,
    float* __restrict__ proj)
{
  const int rb = blockIdx.x * 8;
  const int ob = blockIdx.y * 128;
  const int tid = threadIdx.x;
  __shared__ float xt[8*132];
  __shared__ float wt[128*132];
  {
    int r = tid >> 5, kq = (tid & 31) * 4;
    float4 v = *(const float4*)(resf + (size_t)(rb + r)*RD_ + kq);
    xt[r*132+kq]=v.x; xt[r*132+kq+1]=v.y; xt[r*132+kq+2]=v.z; xt[r*132+kq+3]=v.w;
  }
  for (int m = 0; m < 16; ++m) {
    int idx = m*256 + tid;
    int r = idx >> 5, kq = (idx & 31) * 4;
    int o = ob + r;
    float4 v;
    if (o < 384)        v = *(const float4*)(Wq  + (size_t)o*RD_ + kq);
    else if (o < 768)   v = *(const float4*)(Wk  + (size_t)(o-384)*RD_ + kq);
    else if (o < 1152)  v = *(const float4*)(Wv  + (size_t)(o-768)*RD_ + kq);
    else if (o < 1440)  v = *(const float4*)(Wqp + (size_t)(o-1152)*RD_ + kq);
    else if (o < 1728)  v = *(const float4*)(Wkp + (size_t)(o-1440)*RD_ + kq);
    else if (o < POUT_) v = *(const float4*)(Wvp + (size_t)(o-1728)*RD_ + kq);
    else                v = make_float4(0.f,0.f,0.f,0.f);
    wt[r*132+kq]=v.x; wt[r*132+kq+1]=v.y; wt[r*132+kq+2]=v.z; wt[r*132+kq+3]=v.w;
  }
  __syncthreads();
  const int tt = tid & 7, g = tid >> 3;
  float acc0=0.f, acc1=0.f, acc2=0.f, acc3=0.f;
  #pragma unroll 4
  for (int k2 = 0; k2 < RD_; ++k2) {
    float xv = xt[tt*132 + k2];
    acc0 += xv * wt[(g     )*132 + k2];
    acc1 += xv * wt[(g + 32)*132 + k2];
    acc2 += xv * wt[(g + 64)*132 + k2];
    acc3 += xv * wt[(g + 96)*132 + k2];
  }
  float* dst = proj + (size_t)(rb + tt)*POUT_ + ob;
  if (ob + g      < POUT_) dst[g]      = acc0;
  if (ob + g + 32 < POUT_) dst[g+32]   = acc1;
  if (ob + g + 64 < POUT_) dst[g+64]   = acc2;
  if (ob + g + 96 < POUT_) dst[g+96]   = acc3;
}

// ---------------------------------------------------------------------------
// K2: per-token rotate + build Q~/K~ (58-dim augmented, padded to 64)
// ---------------------------------------------------------------------------
__global__ __launch_bounds__(64) void k_rot(
    const float* __restrict__ R, const float* __restrict__ coord,
    const float* __restrict__ spc, const float* __restrict__ proj,
    float* __restrict__ qt, float* __restrict__ kt, float* __restrict__ vpg)
{
  const int t = blockIdx.x;
  const int n = t / L_, i = t % L_;
  const int tid = threadIdx.x;
  __shared__ float prow[POUT_];
  __shared__ float qpl[288], kpl[288], vpl[288];
  __shared__ float qqs[H_], kks[H_], coefs[H_];
  for (int m = tid; m < POUT_/4; m += 64)
    ((float4*)prow)[m] = *((const float4*)(proj + (size_t)t*POUT_) + m);
  if (tid < H_) coefs[tid] = -log1pf(expf(spc[tid])) * (1.0f/12.0f);
  __syncthreads();
  const float* Rm = R + (size_t)t*9;
  const float r00=Rm[0],r01=Rm[1],r02=Rm[2],r10=Rm[3],r11=Rm[4],r12=Rm[5],r20=Rm[6],r21=Rm[7],r22=Rm[8];
  const float cx = coord[(size_t)t*3], cy = coord[(size_t)t*3+1], cz = coord[(size_t)t*3+2];
  for (int idx = tid; idx < 288; idx += 64) {
    int mat = idx / 96, p = idx % 96;
    const float* s = prow + 1152 + mat*288 + p*3;
    float px=s[0], py=s[1], pz=s[2];
    float gx = r00*px + r01*py + r02*pz + cx;
    float gy = r10*px + r11*py + r12*pz + cy;
    float gz = r20*px + r21*py + r22*pz + cz;
    float* d = (mat==0? qpl : mat==1? kpl : vpl) + p*3;
    d[0]=gx; d[1]=gy; d[2]=gz;
  }
  __syncthreads();
  if (tid < 24) {
    int mat = tid / H_, h = tid % H_;
    const float* s = (mat==0? qpl : kpl) + h*24;
    float acc = 0.f;
    #pragma unroll
    for (int c2 = 0; c2 < 24; ++c2) acc += s[c2]*s[c2];
    (mat==0? qqs : kks)[h] = acc;
  }
  for (int m = tid; m < 72; m += 64)
    ((float4*)(vpg + (size_t)t*288))[m] = ((float4*)vpl)[m];
  __syncthreads();
  for (int idx = tid; idx < 2*H_*64; idx += 64) {
    int which = idx / 768, rem = idx % 768, h = rem >> 6, c = rem & 63;
    float val;
    if (which == 0) {
      if (c < 32)       val = prow[h*32 + c] * ISQD_;
      else if (c < 56)  val = qpl[h*24 + (c-32)] * (-2.0f * coefs[h]);
      else if (c == 56) val = coefs[h] * qqs[h];
      else if (c == 57) val = coefs[h];
      else              val = 0.f;
      qt[((size_t)(n*H_ + h)*L_ + i)*64 + c] = val;
    } else {
      if (c < 32)       val = prow[384 + h*32 + c];
      else if (c < 56)  val = kpl[h*24 + (c-32)];
      else if (c == 56) val = 1.0f;
      else if (c == 57) val = kks[h];
      else              val = 0.f;
      kt[((size_t)(n*H_ + h)*L_ + i)*64 + c] = val;
    }
  }
}

// ---------------------------------------------------------------------------
// K3: logits GEMM (node+spatial): lgal[n][h][i][j] = Qt[i] . Kt[j]  (raw)
// ---------------------------------------------------------------------------
__global__ __launch_bounds__(256) void k_lgns(
    const float* __restrict__ qt, const float* __restrict__ kt,
    float* __restrict__ lgal)
{
  const int jb = blockIdx.x * 64, ib = blockIdx.y * 64, nh = blockIdx.z;
  const int tid = threadIdx.x;
  __shared__ float qs[64*65], ks[64*65];
  for (int m = 0; m < 4; ++m) {
    int idx = m*256 + tid;
    int r = idx >> 4, kq = (idx & 15) * 4;
    float4 a = *(const float4*)(qt + ((size_t)nh*L_ + ib + r)*64 + kq);
    qs[r*65+kq]=a.x; qs[r*65+kq+1]=a.y; qs[r*65+kq+2]=a.z; qs[r*65+kq+3]=a.w;
    float4 b = *(const float4*)(kt + ((size_t)nh*L_ + jb + r)*64 + kq);
    ks[r*65+kq]=b.x; ks[r*65+kq+1]=b.y; ks[r*65+kq+2]=b.z; ks[r*65+kq+3]=b.w;
  }
  __syncthreads();
  const int tx = tid & 15, ty = tid >> 4;
  const int i0 = ty*4, j0 = tx*4;
  float acc[4][4] = {};
  #pragma unroll 2
  for (int k2 = 0; k2 < 64; ++k2) {
    float qv[4], kv[4];
    #pragma unroll
    for (int d = 0; d < 4; ++d) { qv[d] = qs[(i0+d)*65 + k2]; kv[d] = ks[(j0+d)*65 + k2]; }
    #pragma unroll
    for (int a2 = 0; a2 < 4; ++a2)
      #pragma unroll
      for (int b2 = 0; b2 < 4; ++b2) acc[a2][b2] += qv[a2]*kv[b2];
  }
  #pragma unroll
  for (int a2 = 0; a2 < 4; ++a2) {
    float4 v = make_float4(acc[a2][0], acc[a2][1], acc[a2][2], acc[a2][3]);
    *(float4*)(lgal + ((size_t)nh*L_ + ib + i0 + a2)*L_ + jb + j0) = v;
  }
}

// ---------------------------------------------------------------------------
// K4: pair bias + mask + scale (RMW lgal). Block = (jt2 128j, i, n).
// Two 64-j tiles with register ping-pong staging to hide HBM latency.
// lane = j-row (stride-67 = conflict-free), wave = head-triple {w,w+4,w+8}.
// ---------------------------------------------------------------------------
__global__ __launch_bounds__(256) void k_pbias(
    const float* __restrict__ pair, const int* __restrict__ mask,
    const float* __restrict__ Wpb, float* __restrict__ lgal)
{
  const int jt2 = blockIdx.x, i = blockIdx.y, n = blockIdx.z;
  const int bi = n*L_ + i;
  const int tid = threadIdx.x;
  __shared__ float pt[2][64*67];
  const int sr = tid >> 4, scq = (tid & 15)*4;
  // stage tile 0
  #pragma unroll
  for (int m = 0; m < 4; ++m) {
    int r = m*16 + sr;
    float4 v = *(const float4*)(pair + ((size_t)bi*L_ + jt2*128 + r)*PD_ + scq);
    float* d = pt[0] + r*67 + scq;
    d[0]=v.x; d[1]=v.y; d[2]=v.z; d[3]=v.w;
  }
  __syncthreads();
  // issue tile-1 loads into registers (overlaps tile-0 compute)
  float4 rg[4];
  #pragma unroll
  for (int m = 0; m < 4; ++m) {
    int r = m*16 + sr;
    rg[m] = *(const float4*)(pair + ((size_t)bi*L_ + jt2*128 + 64 + r)*PD_ + scq);
  }

  const int r = tid & 63;
  const int w = __builtin_amdgcn_readfirstlane(tid >> 6);
  const float* w0 = Wpb + (w    )*64;
  const float* w1 = Wpb + (w + 4)*64;
  const float* w2 = Wpb + (w + 8)*64;
  const int mi = mask[bi];

  // ---- compute tile 0 ----
  {
    const int j = jt2*128 + r;
    const float* pr = pt[0] + r*67;
    float a0=0.f, a1=0.f, a2=0.f;
    #pragma unroll 16
    for (int c = 0; c < 64; ++c) {
      float pv = pr[c];
      a0 += pv*w0[c]; a1 += pv*w1[c]; a2 += pv*w2[c];
    }
    const float mt = (mi && mask[n*L_ + j]) ? 0.f : -INF_;
    size_t base = ((size_t)(n*H_ + w)*L_ + i)*L_ + j;
    float l0 = lgal[base], l1 = lgal[base + 4*LL_], l2 = lgal[base + 8*LL_];
    lgal[base        ] = (l0 + a0)*ISQ3_ + mt;
    lgal[base + 4*LL_] = (l1 + a1)*ISQ3_ + mt;
    lgal[base + 8*LL_] = (l2 + a2)*ISQ3_ + mt;
  }

  // write tile-1 regs to LDS, then compute
  #pragma unroll
  for (int m = 0; m < 4; ++m) {
    int rr = m*16 + sr;
    float* d = pt[1] + rr*67 + scq;
    d[0]=rg[m].x; d[1]=rg[m].y; d[2]=rg[m].z; d[3]=rg[m].w;
  }
  __syncthreads();
  {
    const int j = jt2*128 + 64 + r;
    const float* pr = pt[1] + r*67;
    float a0=0.f, a1=0.f, a2=0.f;
    #pragma unroll 16
    for (int c = 0; c < 64; ++c) {
      float pv = pr[c];
      a0 += pv*w0[c]; a1 += pv*w1[c]; a2 += pv*w2[c];
    }
    const float mt = (mi && mask[n*L_ + j]) ? 0.f : -INF_;
    size_t base = ((size_t)(n*H_ + w)*L_ + i)*L_ + j;
    float l0 = lgal[base], l1 = lgal[base + 4*LL_], l2 = lgal[base + 8*LL_];
    lgal[base        ] = (l0 + a0)*ISQ3_ + mt;
    lgal[base + 4*LL_] = (l1 + a1)*ISQ3_ + mt;
    lgal[base + 8*LL_] = (l2 + a2)*ISQ3_ + mt;
  }
}

// ---------------------------------------------------------------------------
// K5: softmax per (n,h,i) row, one wave per row, row held in registers.
// ---------------------------------------------------------------------------
__global__ __launch_bounds__(256) void k_softx(
    const int* __restrict__ mask, float* __restrict__ lgal)
{
  const int tid = threadIdx.x;
  const int wid = tid >> 6, lane = tid & 63;
  const int rid = blockIdx.x*4 + wid;          // (n*H+h)*L + i
  const int i = rid & (L_-1);
  const int nh = rid >> 9;
  const int n = nh / H_;
  float4* r4 = (float4*)(lgal + (size_t)rid * L_);
  float4 p0 = r4[lane], p1 = r4[lane + 64];
  float mx = fmaxf(fmaxf(fmaxf(p0.x,p0.y),fmaxf(p0.z,p0.w)),
                   fmaxf(fmaxf(p1.x,p1.y),fmaxf(p1.z,p1.w)));
  #pragma unroll
  for (int off = 1; off < 64; off <<= 1) mx = fmaxf(mx, __shfl_xor(mx, off, 64));
  p0.x = expf(p0.x - mx); p0.y = expf(p0.y - mx);
  p0.z = expf(p0.z - mx); p0.w = expf(p0.w - mx);
  p1.x = expf(p1.x - mx); p1.y = expf(p1.y - mx);
  p1.z = expf(p1.z - mx); p1.w = expf(p1.w - mx);
  float s = p0.x+p0.y+p0.z+p0.w + p1.x+p1.y+p1.z+p1.w;
  #pragma unroll
  for (int off = 1; off < 64; off <<= 1) s += __shfl_xor(s, off, 64);
  const float inv = (mask[n*L_ + i] ? 1.f : 0.f) / s;
  p0.x*=inv; p0.y*=inv; p0.z*=inv; p0.w*=inv;
  p1.x*=inv; p1.y*=inv; p1.z*=inv; p1.w*=inv;
  r4[lane] = p0; r4[lane + 64] = p1;
}

// ---------------------------------------------------------------------------
// K6: feat_pair. Block = (i, n), 4 waves. Wave w owns j in [w*128,w*128+128).
// Lane l = (js = l>>4, cq = (l&15)*4): one dwordx4 per wave = 4 j-rows x 64 c
// = 1KB contiguous. All 12 heads accumulate in float4 acc[12] (VGPRs);
// alpha per-lane loads (16-lane same-address merge). No scalar-load chain,
// no barriers in the loop. Epilogue: shfl js-reduce + LDS cross-wave reduce.
// ---------------------------------------------------------------------------
__global__ __launch_bounds__(256) void k_paggr(
    const float* __restrict__ pair, const float* __restrict__ lgal,
    float* __restrict__ feat)
{
  const int i = blockIdx.x, n = blockIdx.y;
  const int bi = n*L_ + i;
  const int tid = threadIdx.x;
  const int w = tid >> 6, l = tid & 63;
  const int js = l >> 4, cq = (l & 15) << 2;
  __shared__ float part[4][H_][64];

  const float* pb = pair + ((size_t)bi*L_ + w*128 + js)*PD_ + cq;
  const float* ab[H_];
  #pragma unroll
  for (int h = 0; h < H_; ++h)
    ab[h] = lgal + ((size_t)(n*H_ + h)*L_ + i)*L_ + w*128 + js;

  float4 acc[H_];
  #pragma unroll
  for (int h = 0; h < H_; ++h) acc[h] = make_float4(0.f,0.f,0.f,0.f);

  #pragma unroll 2
  for (int g = 0; g < 32; ++g) {
    float4 pv = *(const float4*)(pb + (size_t)g*4*PD_);
    #pragma unroll
    for (int h = 0; h < H_; ++h) {
      float av = ab[h][g*4];
      acc[h].x += av*pv.x; acc[h].y += av*pv.y;
      acc[h].z += av*pv.z; acc[h].w += av*pv.w;
    }
  }

  // reduce across js (lanes differing by 16, 32)
  #pragma unroll
  for (int h = 0; h < H_; ++h) {
    acc[h].x += __shfl_xor(acc[h].x, 16, 64);
    acc[h].y += __shfl_xor(acc[h].y, 16, 64);
    acc[h].z += __shfl_xor(acc[h].z, 16, 64);
    acc[h].w += __shfl_xor(acc[h].w, 16, 64);
    acc[h].x += __shfl_xor(acc[h].x, 32, 64);
    acc[h].y += __shfl_xor(acc[h].y, 32, 64);
    acc[h].z += __shfl_xor(acc[h].z, 32, 64);
    acc[h].w += __shfl_xor(acc[h].w, 32, 64);
  }
  if (l < 16) {
    #pragma unroll
    for (int h = 0; h < H_; ++h)
      *(float4*)(&part[w][h][cq]) = acc[h];
  }
  __syncthreads();
  for (int u = tid; u < H_*64; u += 256) {
    int h = u >> 6, c = u & 63;
    feat[(size_t)bi*FEAT_ + h*64 + c] =
        part[0][h][c] + part[1][h][c] + part[2][h][c] + part[3][h][c];
  }
}

// ---------------------------------------------------------------------------
// K7: per (n,h,z) GEMM partials: C[i, 0:56] = alpha[i, z*256+j] @ [v|vp]
// pav[z][nh][i][56]
// ---------------------------------------------------------------------------
__global__ __launch_bounds__(256) void k_av(
    const float* __restrict__ lgal, const float* __restrict__ proj,
    const float* __restrict__ vpg, float* __restrict__ pav)
{
  const int ib = blockIdx.x * 64;
  const int nh = blockIdx.y;
  const int z  = blockIdx.z;
  const int n = nh / H_, h = nh % H_, nL = n*L_;
  const int tid = threadIdx.x;
  __shared__ float as[64*65];
  __shared__ float bs[64*60];
  const int tx = tid & 15, ty = tid >> 4;
  const int i0 = ty*4, c0 = tx*4;
  float acc[4][4] = {};
  for (int jb = z*256; jb < z*256 + 256; jb += 64) {
    for (int m = 0; m < 4; ++m) {
      int idx = m*256 + tid;
      int r = idx >> 4, jq = (idx & 15) * 4;
      float4 a = *(const float4*)(lgal + ((size_t)nh*L_ + ib + r)*L_ + jb + jq);
      as[r*65+jq]=a.x; as[r*65+jq+1]=a.y; as[r*65+jq+2]=a.z; as[r*65+jq+3]=a.w;
    }
    for (int m = 0; m < 4; ++m) {
      int idx = m*256 + tid;
      int j = idx >> 4, qq = idx & 15;
      if (qq < 14) {
        float4 v;
        if (qq < 8) v = *(const float4*)(proj + (size_t)(nL + jb + j)*POUT_ + 768 + h*32 + qq*4);
        else        v = *(const float4*)(vpg  + (size_t)(nL + jb + j)*288  + h*24 + (qq-8)*4);
        float* d = bs + j*60 + qq*4;
        d[0]=v.x; d[1]=v.y; d[2]=v.z; d[3]=v.w;
      }
    }
    __syncthreads();
    #pragma unroll 2
    for (int k2 = 0; k2 < 64; ++k2) {
      float av[4];
      #pragma unroll
      for (int d = 0; d < 4; ++d) av[d] = as[(i0+d)*65 + k2];
      float4 bv = *(const float4*)(bs + k2*60 + c0);
      #pragma unroll
      for (int a2 = 0; a2 < 4; ++a2) {
        acc[a2][0] += av[a2]*bv.x; acc[a2][1] += av[a2]*bv.y;
        acc[a2][2] += av[a2]*bv.z; acc[a2][3] += av[a2]*bv.w;
      }
    }
    __syncthreads();
  }
  if (c0 < 56) {
    #pragma unroll
    for (int a2 = 0; a2 < 4; ++a2)
      *(float4*)(pav + (((size_t)z*24 + nh)*L_ + ib + i0 + a2)*56 + c0) =
          make_float4(acc[a2][0], acc[a2][1], acc[a2][2], acc[a2][3]);
  }
}

// ---------------------------------------------------------------------------
// K8: reduce k_av partials -> feat_node + aggr
// ---------------------------------------------------------------------------
__global__ __launch_bounds__(256) void k_avred(
    const float* __restrict__ pav, float* __restrict__ feat,
    float* __restrict__ aggr)
{
  const int tok = blockIdx.x, tid = threadIdx.x;
  const int n = tok / L_, i = tok % L_;
  float* fb = feat + (size_t)tok*FEAT_;
  float* ag = aggr + (size_t)tok*288;
  for (int u = tid; u < 672; u += 256) {
    int h = u / 56, c = u % 56;
    size_t off = (((size_t)(n*H_ + h))*L_ + i)*56 + c;
    float v = pav[off] + pav[off + (size_t)24*L_*56];
    if (c < 32) fb[768 + h*32 + c] = v;
    else        ag[h*24 + (c - 32)] = v;
  }
}

// ---------------------------------------------------------------------------
// K9: per-token point post-process: local frame, dist, dir
// ---------------------------------------------------------------------------
__global__ __launch_bounds__(128) void k_post(
    const float* __restrict__ R, const float* __restrict__ coord,
    const float* __restrict__ aggr, float* __restrict__ feat)
{
  const int t = blockIdx.x, tid = threadIdx.x;
  if (tid >= 96) return;
  const float* Rm = R + (size_t)t*9;
  const float cx = coord[(size_t)t*3], cy = coord[(size_t)t*3+1], cz = coord[(size_t)t*3+2];
  const float* ag = aggr + (size_t)t*288;
  float* fb = feat + (size_t)t*FEAT_;
  float dx = ag[tid*3] - cx, dy = ag[tid*3+1] - cy, dz = ag[tid*3+2] - cz;
  float fx = Rm[0]*dx + Rm[3]*dy + Rm[6]*dz;
  float fy = Rm[1]*dx + Rm[4]*dy + Rm[7]*dz;
  float fz = Rm[2]*dx + Rm[5]*dy + Rm[8]*dz;
  float dist = sqrtf(fx*fx + fy*fy + fz*fz);
  float idn = 1.f/(dist + 1e-4f);
  fb[1152+tid*3]=fx; fb[1152+tid*3+1]=fy; fb[1152+tid*3+2]=fz;
  fb[1440+tid]=dist;
  fb[1536+tid*3]=fx*idn; fb[1536+tid*3+1]=fy*idn; fb[1536+tid*3+2]=fz*idn;
}

// ---------------------------------------------------------------------------
// K10: y = feat @ Wout^T.  8 tokens x 64 outputs per block.
// ---------------------------------------------------------------------------
__global__ __launch_bounds__(256) void k_y_gemm(
    const float* __restrict__ feat, const float* __restrict__ Wout,
    float* __restrict__ ybuf)
{
  const int rb = blockIdx.x * 8;
  const int ob = blockIdx.y * 64;
  const int tid = threadIdx.x;
  __shared__ float wt[96*65];   // [k][out], padded
  __shared__ float ft[96*10];   // [k][tok], padded
  const int o = tid & 63, tg = tid >> 6;     // tokens tg*2, tg*2+1
  float acc0 = 0.f, acc1 = 0.f;
  for (int kb = 0; kb < FEAT_; kb += 96) {
    for (int m = 0; m < 6; ++m) {
      int idx = m*256 + tid;
      int r = idx / 24, cq = (idx % 24) * 4;
      float4 v = *(const float4*)(Wout + (size_t)(ob + r)*FEAT_ + kb + cq);
      wt[(cq  )*65 + r] = v.x;
      wt[(cq+1)*65 + r] = v.y;
      wt[(cq+2)*65 + r] = v.z;
      wt[(cq+3)*65 + r] = v.w;
    }
    if (tid < 192) {
      int t = tid / 24, cq = (tid % 24) * 4;
      float4 v = *(const float4*)(feat + (size_t)(rb + t)*FEAT_ + kb + cq);
      ft[(cq  )*10 + t] = v.x;
      ft[(cq+1)*10 + t] = v.y;
      ft[(cq+2)*10 + t] = v.z;
      ft[(cq+3)*10 + t] = v.w;
    }
    __syncthreads();
    #pragma unroll 4
    for (int k2 = 0; k2 < 96; ++k2) {
      float wv = wt[k2*65 + o];
      float2 fv = *(const float2*)(ft + k2*10 + tg*2);
      acc0 += wv * fv.x;
      acc1 += wv * fv.y;
    }
    __syncthreads();
  }
  ybuf[(size_t)(rb + tg*2    )*RD_ + ob + o] = acc0;
  ybuf[(size_t)(rb + tg*2 + 1)*RD_ + ob + o] = acc1;
}

// ---------------------------------------------------------------------------
// K11: per token: bias/mask/residual + LN1 + MLP + LN2
// ---------------------------------------------------------------------------
__device__ __forceinline__ float bsum128(float v, float* red, int tid) {
  #pragma unroll
  for (int off = 1; off < 64; off <<= 1) v += __shfl_xor(v, off, 64);
  __syncthreads();
  if ((tid & 63) == 0) red[tid >> 6] = v;
  __syncthreads();
  return red[0] + red[1];
}

__global__ __launch_bounds__(128) void k_mlp(
    const float* __restrict__ resf, const int* __restrict__ mask,
    const float* __restrict__ ybuf, const float* __restrict__ bout,
    const float* __restrict__ Wm1, const float* __restrict__ bm1,
    const float* __restrict__ Wm2, const float* __restrict__ bm2,
    const float* __restrict__ Wm3, const float* __restrict__ bm3,
    const float* __restrict__ g1, const float* __restrict__ b1,
    const float* __restrict__ g2, const float* __restrict__ b2,
    float* __restrict__ out)
{
  const int t = blockIdx.x, tid = threadIdx.x;
  __shared__ float xb[RD_], h1b[RD_], h2b[RD_];
  __shared__ float red[2];
  float acc = ybuf[(size_t)t*RD_ + tid] + bout[tid];
  if (mask[t] == 0) acc = 0.f;
  float r = resf[(size_t)t*RD_ + tid] + acc;

  float mean = bsum128(r, red, tid) * (1.f/RD_);
  float d = r - mean;
  float var = bsum128(d*d, red, tid) * (1.f/RD_);
  float xn = d * rsqrtf(var + 1e-5f) * g1[tid] + b1[tid];
  xb[tid] = xn;
  __syncthreads();

  float a1 = bm1[tid];
  {
    const float4* w4 = (const float4*)(Wm1 + (size_t)tid*RD_);
    #pragma unroll
    for (int c = 0; c < RD_/4; ++c) { float4 a = w4[c]; a1 += a.x*xb[4*c]+a.y*xb[4*c+1]+a.z*xb[4*c+2]+a.w*xb[4*c+3]; }
  }
  a1 = fmaxf(a1, 0.f);
  h1b[tid] = a1;
  __syncthreads();

  float a2 = bm2[tid];
  {
    const float4* w4 = (const float4*)(Wm2 + (size_t)tid*RD_);
    #pragma unroll
    for (int c = 0; c < RD_/4; ++c) { float4 a = w4[c]; a2 += a.x*h1b[4*c]+a.y*h1b[4*c+1]+a.z*h1b[4*c+2]+a.w*h1b[4*c+3]; }
  }
  a2 = fmaxf(a2, 0.f);
  h2b[tid] = a2;
  __syncthreads();

  float a3 = bm3[tid];
  {
    const float4* w4 = (const float4*)(Wm3 + (size_t)tid*RD_);
    #pragma unroll
    for (int c = 0; c < RD_/4; ++c) { float4 a = w4[c]; a3 += a.x*h2b[4*c]+a.y*h2b[4*c+1]+a.z*h2b[4*c+2]+a.w*h2b[4*c+3]; }
  }
  float r2 = xn + a3;
  float mean2 = bsum128(r2, red, tid) * (1.f/RD_);
  float d2 = r2 - mean2;
  float var2 = bsum128(d2*d2, red, tid) * (1.f/RD_);
  out[(size_t)t*RD_ + tid] = d2 * rsqrtf(var2 + 1e-5f) * g2[tid] + b2[tid];
}

// ---------------------------------------------------------------------------
extern "C" void kernel_launch(void* const* d_in, const int* in_sizes, int n_in,
                              void* d_out, int out_size, void* d_ws, size_t ws_size,
                              hipStream_t stream) {
  (void)in_sizes; (void)n_in; (void)out_size; (void)ws_size;
  const float* R     = (const float*)d_in[0];
  const float* coord = (const float*)d_in[1];
  const float* resf  = (const float*)d_in[2];
  const float* pair  = (const float*)d_in[3];
  const int*   mask  = (const int*)  d_in[4];
  const float* Wq    = (const float*)d_in[5];
  const float* Wk    = (const float*)d_in[6];
  const float* Wv    = (const float*)d_in[7];
  const float* Wpb   = (const float*)d_in[8];
  const float* spc   = (const float*)d_in[9];
  const float* Wqp   = (const float*)d_in[10];
  const float* Wkp   = (const float*)d_in[11];
  const float* Wvp   = (const float*)d_in[12];
  const float* Wout  = (const float*)d_in[13];
  const float* bout  = (const float*)d_in[14];
  const float* Wm1   = (const float*)d_in[15];
  const float* bm1   = (const float*)d_in[16];
  const float* Wm2   = (const float*)d_in[17];
  const float* bm2   = (const float*)d_in[18];
  const float* Wm3   = (const float*)d_in[19];
  const float* bm3   = (const float*)d_in[20];
  const float* g1    = (const float*)d_in[21];
  const float* b1    = (const float*)d_in[22];
  const float* g2    = (const float*)d_in[23];
  const float* b2    = (const float*)d_in[24];

  float* ws   = (float*)d_ws;
  float* proj = ws;                               // NL*2016
  float* qt   = proj + (size_t)NL_*POUT_;         // 24*512*64  (dead after k_lgns)
  float* kt   = qt   + (size_t)N_*H_*L_*64;       // 24*512*64  (dead after k_lgns)
  float* vpg  = kt   + (size_t)N_*H_*L_*64;       // NL*288
  float* lgal = vpg  + (size_t)NL_*288;           // 24*512*512 (logits -> alpha)
  float* feat = lgal + (size_t)N_*H_*L_*L_;       // NL*1824
  float* ybuf = feat + (size_t)NL_*FEAT_;         // NL*128
  float* aggr = ybuf + (size_t)NL_*RD_;           // NL*288
  float* pav  = qt;                               // 2*24*512*56 floats (5.5MB) <= qt+kt

  k_proj_gemm<<<dim3(NL_/8, 16), 256, 0, stream>>>(resf, Wq, Wk, Wv, Wqp, Wkp, Wvp, proj);
  k_rot<<<NL_, 64, 0, stream>>>(R, coord, spc, proj, qt, kt, vpg);
  k_lgns<<<dim3(L_/64, L_/64, N_*H_), 256, 0, stream>>>(qt, kt, lgal);
  k_pbias<<<dim3(L_/128, L_, N_), 256, 0, stream>>>(pair, mask, Wpb, lgal);
  k_softx<<<(N_*H_*L_)/4, 256, 0, stream>>>(mask, lgal);
  k_paggr<<<dim3(L_, N_), 256, 0, stream>>>(pair, lgal, feat);
  k_av<<<dim3(L_/64, N_*H_, 2), 256, 0, stream>>>(lgal, proj, vpg, pav);
  k_avred<<<NL_, 256, 0, stream>>>(pav, feat, aggr);
  k_post<<<NL_, 128, 0, stream>>>(R, coord, aggr, feat);
  k_y_gemm<<<dim3(NL_/8, 2), 256, 0, stream>>>(feat, Wout, ybuf);
  k_mlp<<<NL_, 128, 0, stream>>>(resf, mask, ybuf, bout, Wm1, bm1, Wm2, bm2, Wm3, bm3,
                                 g1, b1, g2, b2, (float*)d_out);
}

// Round 8
// 243.856 us; speedup vs baseline: 1.3580x; 1.0023x over previous
//
#include <hip/hip_runtime.h>
#include <hip/hip_bf16.h>

#define N_ 2
#define L_ 512
#define RD_ 128
#define PD_ 64
#define H_ 12
#define NL_ (N_*L_)
#define POUT_ 2016          /* 3*384 + 3*288 */
#define FEAT_ 1824
#define INF_ 100000.0f
#define ISQD_ 0.17677669529663687f   /* 1/sqrt(32) */
#define ISQ3_ 0.5773502691896258f    /* sqrt(1/3) */
#define LL_ ((size_t)L_*L_)

// ---------------------------------------------------------------------------
// K1: projection GEMM. proj[token][2016] = resf @ [Wq|Wk|Wv|Wqp|Wkp|Wvp]^T
// ---------------------------------------------------------------------------
__global__ __launch_bounds__(256) void k_proj_gemm(
    const float* __restrict__ resf,
    const float* __restrict__ Wq, const float* __restrict__ Wk, const float* __restrict__ Wv,
    const float* __restrict__ Wqp, const float* __restrict__ Wkp, const float* __restrict__ Wvp,
    float* __restrict__ proj)
{
  const int rb = blockIdx.x * 8;
  const int ob = blockIdx.y * 128;
  const int tid = threadIdx.x;
  __shared__ float xt[8*132];
  __shared__ float wt[128*132];
  {
    int r = tid >> 5, kq = (tid & 31) * 4;
    float4 v = *(const float4*)(resf + (size_t)(rb + r)*RD_ + kq);
    xt[r*132+kq]=v.x; xt[r*132+kq+1]=v.y; xt[r*132+kq+2]=v.z; xt[r*132+kq+3]=v.w;
  }
  for (int m = 0; m < 16; ++m) {
    int idx = m*256 + tid;
    int r = idx >> 5, kq = (idx & 31) * 4;
    int o = ob + r;
    float4 v;
    if (o < 384)        v = *(const float4*)(Wq  + (size_t)o*RD_ + kq);
    else if (o < 768)   v = *(const float4*)(Wk  + (size_t)(o-384)*RD_ + kq);
    else if (o < 1152)  v = *(const float4*)(Wv  + (size_t)(o-768)*RD_ + kq);
    else if (o < 1440)  v = *(const float4*)(Wqp + (size_t)(o-1152)*RD_ + kq);
    else if (o < 1728)  v = *(const float4*)(Wkp + (size_t)(o-1440)*RD_ + kq);
    else if (o < POUT_) v = *(const float4*)(Wvp + (size_t)(o-1728)*RD_ + kq);
    else                v = make_float4(0.f,0.f,0.f,0.f);
    wt[r*132+kq]=v.x; wt[r*132+kq+1]=v.y; wt[r*132+kq+2]=v.z; wt[r*132+kq+3]=v.w;
  }
  __syncthreads();
  const int tt = tid & 7, g = tid >> 3;
  float acc0=0.f, acc1=0.f, acc2=0.f, acc3=0.f;
  #pragma unroll 4
  for (int k2 = 0; k2 < RD_; ++k2) {
    float xv = xt[tt*132 + k2];
    acc0 += xv * wt[(g     )*132 + k2];
    acc1 += xv * wt[(g + 32)*132 + k2];
    acc2 += xv * wt[(g + 64)*132 + k2];
    acc3 += xv * wt[(g + 96)*132 + k2];
  }
  float* dst = proj + (size_t)(rb + tt)*POUT_ + ob;
  if (ob + g      < POUT_) dst[g]      = acc0;
  if (ob + g + 32 < POUT_) dst[g+32]   = acc1;
  if (ob + g + 64 < POUT_) dst[g+64]   = acc2;
  if (ob + g + 96 < POUT_) dst[g+96]   = acc3;
}

// ---------------------------------------------------------------------------
// K2: per-token rotate + build Q~/K~ (58-dim augmented, padded to 64)
// ---------------------------------------------------------------------------
__global__ __launch_bounds__(64) void k_rot(
    const float* __restrict__ R, const float* __restrict__ coord,
    const float* __restrict__ spc, const float* __restrict__ proj,
    float* __restrict__ qt, float* __restrict__ kt, float* __restrict__ vpg)
{
  const int t = blockIdx.x;
  const int n = t / L_, i = t % L_;
  const int tid = threadIdx.x;
  __shared__ float prow[POUT_];
  __shared__ float qpl[288], kpl[288], vpl[288];
  __shared__ float qqs[H_], kks[H_], coefs[H_];
  for (int m = tid; m < POUT_/4; m += 64)
    ((float4*)prow)[m] = *((const float4*)(proj + (size_t)t*POUT_) + m);
  if (tid < H_) coefs[tid] = -log1pf(expf(spc[tid])) * (1.0f/12.0f);
  __syncthreads();
  const float* Rm = R + (size_t)t*9;
  const float r00=Rm[0],r01=Rm[1],r02=Rm[2],r10=Rm[3],r11=Rm[4],r12=Rm[5],r20=Rm[6],r21=Rm[7],r22=Rm[8];
  const float cx = coord[(size_t)t*3], cy = coord[(size_t)t*3+1], cz = coord[(size_t)t*3+2];
  for (int idx = tid; idx < 288; idx += 64) {
    int mat = idx / 96, p = idx % 96;
    const float* s = prow + 1152 + mat*288 + p*3;
    float px=s[0], py=s[1], pz=s[2];
    float gx = r00*px + r01*py + r02*pz + cx;
    float gy = r10*px + r11*py + r12*pz + cy;
    float gz = r20*px + r21*py + r22*pz + cz;
    float* d = (mat==0? qpl : mat==1? kpl : vpl) + p*3;
    d[0]=gx; d[1]=gy; d[2]=gz;
  }
  __syncthreads();
  if (tid < 24) {
    int mat = tid / H_, h = tid % H_;
    const float* s = (mat==0? qpl : kpl) + h*24;
    float acc = 0.f;
    #pragma unroll
    for (int c2 = 0; c2 < 24; ++c2) acc += s[c2]*s[c2];
    (mat==0? qqs : kks)[h] = acc;
  }
  for (int m = tid; m < 72; m += 64)
    ((float4*)(vpg + (size_t)t*288))[m] = ((float4*)vpl)[m];
  __syncthreads();
  for (int idx = tid; idx < 2*H_*64; idx += 64) {
    int which = idx / 768, rem = idx % 768, h = rem >> 6, c = rem & 63;
    float val;
    if (which == 0) {
      if (c < 32)       val = prow[h*32 + c] * ISQD_;
      else if (c < 56)  val = qpl[h*24 + (c-32)] * (-2.0f * coefs[h]);
      else if (c == 56) val = coefs[h] * qqs[h];
      else if (c == 57) val = coefs[h];
      else              val = 0.f;
      qt[((size_t)(n*H_ + h)*L_ + i)*64 + c] = val;
    } else {
      if (c < 32)       val = prow[384 + h*32 + c];
      else if (c < 56)  val = kpl[h*24 + (c-32)];
      else if (c == 56) val = 1.0f;
      else if (c == 57) val = kks[h];
      else              val = 0.f;
      kt[((size_t)(n*H_ + h)*L_ + i)*64 + c] = val;
    }
  }
}

// ---------------------------------------------------------------------------
// K3: logits GEMM: lgal[n][h][i][j] = Qt[i].Kt[j]. Stride-66 tiles (even ->
// legal b64 reads), float2 over k pairs: 8 b64 reads per 32 FMA.
// ---------------------------------------------------------------------------
__global__ __launch_bounds__(256) void k_lgns(
    const float* __restrict__ qt, const float* __restrict__ kt,
    float* __restrict__ lgal)
{
  const int jb = blockIdx.x * 64, ib = blockIdx.y * 64, nh = blockIdx.z;
  const int tid = threadIdx.x;
  __shared__ float qs[64*66], ks[64*66];
  for (int m = 0; m < 4; ++m) {
    int idx = m*256 + tid;
    int r = idx >> 4, kq = (idx & 15) * 4;
    float4 a = *(const float4*)(qt + ((size_t)nh*L_ + ib + r)*64 + kq);
    qs[r*66+kq]=a.x; qs[r*66+kq+1]=a.y; qs[r*66+kq+2]=a.z; qs[r*66+kq+3]=a.w;
    float4 b = *(const float4*)(kt + ((size_t)nh*L_ + jb + r)*64 + kq);
    ks[r*66+kq]=b.x; ks[r*66+kq+1]=b.y; ks[r*66+kq+2]=b.z; ks[r*66+kq+3]=b.w;
  }
  __syncthreads();
  const int tx = tid & 15, ty = tid >> 4;
  const int i0 = ty*4, j0 = tx*4;
  float acc[4][4] = {};
  #pragma unroll 4
  for (int k2 = 0; k2 < 64; k2 += 2) {
    float2 qv[4], kv[4];
    #pragma unroll
    for (int d = 0; d < 4; ++d) {
      qv[d] = *(const float2*)(qs + (i0+d)*66 + k2);
      kv[d] = *(const float2*)(ks + (j0+d)*66 + k2);
    }
    #pragma unroll
    for (int a2 = 0; a2 < 4; ++a2)
      #pragma unroll
      for (int b2 = 0; b2 < 4; ++b2)
        acc[a2][b2] += qv[a2].x*kv[b2].x + qv[a2].y*kv[b2].y;
  }
  #pragma unroll
  for (int a2 = 0; a2 < 4; ++a2) {
    float4 v = make_float4(acc[a2][0], acc[a2][1], acc[a2][2], acc[a2][3]);
    *(float4*)(lgal + ((size_t)nh*L_ + ib + i0 + a2)*L_ + jb + j0) = v;
  }
}

// ---------------------------------------------------------------------------
// K4: pair bias + mask + scale (RMW lgal). Block = (jt2 128j, i, n).
// ---------------------------------------------------------------------------
__global__ __launch_bounds__(256) void k_pbias(
    const float* __restrict__ pair, const int* __restrict__ mask,
    const float* __restrict__ Wpb, float* __restrict__ lgal)
{
  const int jt2 = blockIdx.x, i = blockIdx.y, n = blockIdx.z;
  const int bi = n*L_ + i;
  const int tid = threadIdx.x;
  __shared__ float pt[2][64*67];
  const int sr = tid >> 4, scq = (tid & 15)*4;
  #pragma unroll
  for (int m = 0; m < 4; ++m) {
    int r = m*16 + sr;
    float4 v = *(const float4*)(pair + ((size_t)bi*L_ + jt2*128 + r)*PD_ + scq);
    float* d = pt[0] + r*67 + scq;
    d[0]=v.x; d[1]=v.y; d[2]=v.z; d[3]=v.w;
  }
  __syncthreads();
  float4 rg[4];
  #pragma unroll
  for (int m = 0; m < 4; ++m) {
    int r = m*16 + sr;
    rg[m] = *(const float4*)(pair + ((size_t)bi*L_ + jt2*128 + 64 + r)*PD_ + scq);
  }

  const int r = tid & 63;
  const int w = __builtin_amdgcn_readfirstlane(tid >> 6);
  const float* w0 = Wpb + (w    )*64;
  const float* w1 = Wpb + (w + 4)*64;
  const float* w2 = Wpb + (w + 8)*64;
  const int mi = mask[bi];

  {
    const int j = jt2*128 + r;
    const float* pr = pt[0] + r*67;
    float a0=0.f, a1=0.f, a2=0.f;
    #pragma unroll 16
    for (int c = 0; c < 64; ++c) {
      float pv = pr[c];
      a0 += pv*w0[c]; a1 += pv*w1[c]; a2 += pv*w2[c];
    }
    const float mt = (mi && mask[n*L_ + j]) ? 0.f : -INF_;
    size_t base = ((size_t)(n*H_ + w)*L_ + i)*L_ + j;
    float l0 = lgal[base], l1 = lgal[base + 4*LL_], l2 = lgal[base + 8*LL_];
    lgal[base        ] = (l0 + a0)*ISQ3_ + mt;
    lgal[base + 4*LL_] = (l1 + a1)*ISQ3_ + mt;
    lgal[base + 8*LL_] = (l2 + a2)*ISQ3_ + mt;
  }

  #pragma unroll
  for (int m = 0; m < 4; ++m) {
    int rr = m*16 + sr;
    float* d = pt[1] + rr*67 + scq;
    d[0]=rg[m].x; d[1]=rg[m].y; d[2]=rg[m].z; d[3]=rg[m].w;
  }
  __syncthreads();
  {
    const int j = jt2*128 + 64 + r;
    const float* pr = pt[1] + r*67;
    float a0=0.f, a1=0.f, a2=0.f;
    #pragma unroll 16
    for (int c = 0; c < 64; ++c) {
      float pv = pr[c];
      a0 += pv*w0[c]; a1 += pv*w1[c]; a2 += pv*w2[c];
    }
    const float mt = (mi && mask[n*L_ + j]) ? 0.f : -INF_;
    size_t base = ((size_t)(n*H_ + w)*L_ + i)*L_ + j;
    float l0 = lgal[base], l1 = lgal[base + 4*LL_], l2 = lgal[base + 8*LL_];
    lgal[base        ] = (l0 + a0)*ISQ3_ + mt;
    lgal[base + 4*LL_] = (l1 + a1)*ISQ3_ + mt;
    lgal[base + 8*LL_] = (l2 + a2)*ISQ3_ + mt;
  }
}

// ---------------------------------------------------------------------------
// K5: softmax per (n,h,i) row, one wave per row, row held in registers.
// ---------------------------------------------------------------------------
__global__ __launch_bounds__(256) void k_softx(
    const int* __restrict__ mask, float* __restrict__ lgal)
{
  const int tid = threadIdx.x;
  const int wid = tid >> 6, lane = tid & 63;
  const int rid = blockIdx.x*4 + wid;          // (n*H+h)*L + i
  const int i = rid & (L_-1);
  const int nh = rid >> 9;
  const int n = nh / H_;
  float4* r4 = (float4*)(lgal + (size_t)rid * L_);
  float4 p0 = r4[lane], p1 = r4[lane + 64];
  float mx = fmaxf(fmaxf(fmaxf(p0.x,p0.y),fmaxf(p0.z,p0.w)),
                   fmaxf(fmaxf(p1.x,p1.y),fmaxf(p1.z,p1.w)));
  #pragma unroll
  for (int off = 1; off < 64; off <<= 1) mx = fmaxf(mx, __shfl_xor(mx, off, 64));
  p0.x = expf(p0.x - mx); p0.y = expf(p0.y - mx);
  p0.z = expf(p0.z - mx); p0.w = expf(p0.w - mx);
  p1.x = expf(p1.x - mx); p1.y = expf(p1.y - mx);
  p1.z = expf(p1.z - mx); p1.w = expf(p1.w - mx);
  float s = p0.x+p0.y+p0.z+p0.w + p1.x+p1.y+p1.z+p1.w;
  #pragma unroll
  for (int off = 1; off < 64; off <<= 1) s += __shfl_xor(s, off, 64);
  const float inv = (mask[n*L_ + i] ? 1.f : 0.f) / s;
  p0.x*=inv; p0.y*=inv; p0.z*=inv; p0.w*=inv;
  p1.x*=inv; p1.y*=inv; p1.z*=inv; p1.w*=inv;
  r4[lane] = p0; r4[lane + 64] = p1;
}

// ---------------------------------------------------------------------------
// K6: feat_pair. Register streaming, no LDS loop, 1KB/wave loads.
// ---------------------------------------------------------------------------
__global__ __launch_bounds__(256) void k_paggr(
    const float* __restrict__ pair, const float* __restrict__ lgal,
    float* __restrict__ feat)
{
  const int i = blockIdx.x, n = blockIdx.y;
  const int bi = n*L_ + i;
  const int tid = threadIdx.x;
  const int w = tid >> 6, l = tid & 63;
  const int js = l >> 4, cq = (l & 15) << 2;
  __shared__ float part[4][H_][64];

  const float* pb = pair + ((size_t)bi*L_ + w*128 + js)*PD_ + cq;
  const float* ab[H_];
  #pragma unroll
  for (int h = 0; h < H_; ++h)
    ab[h] = lgal + ((size_t)(n*H_ + h)*L_ + i)*L_ + w*128 + js;

  float4 acc[H_];
  #pragma unroll
  for (int h = 0; h < H_; ++h) acc[h] = make_float4(0.f,0.f,0.f,0.f);

  #pragma unroll 2
  for (int g = 0; g < 32; ++g) {
    float4 pv = *(const float4*)(pb + (size_t)g*4*PD_);
    #pragma unroll
    for (int h = 0; h < H_; ++h) {
      float av = ab[h][g*4];
      acc[h].x += av*pv.x; acc[h].y += av*pv.y;
      acc[h].z += av*pv.z; acc[h].w += av*pv.w;
    }
  }

  #pragma unroll
  for (int h = 0; h < H_; ++h) {
    acc[h].x += __shfl_xor(acc[h].x, 16, 64);
    acc[h].y += __shfl_xor(acc[h].y, 16, 64);
    acc[h].z += __shfl_xor(acc[h].z, 16, 64);
    acc[h].w += __shfl_xor(acc[h].w, 16, 64);
    acc[h].x += __shfl_xor(acc[h].x, 32, 64);
    acc[h].y += __shfl_xor(acc[h].y, 32, 64);
    acc[h].z += __shfl_xor(acc[h].z, 32, 64);
    acc[h].w += __shfl_xor(acc[h].w, 32, 64);
  }
  if (l < 16) {
    #pragma unroll
    for (int h = 0; h < H_; ++h)
      *(float4*)(&part[w][h][cq]) = acc[h];
  }
  __syncthreads();
  for (int u = tid; u < H_*64; u += 256) {
    int h = u >> 6, c = u & 63;
    feat[(size_t)bi*FEAT_ + h*64 + c] =
        part[0][h][c] + part[1][h][c] + part[2][h][c] + part[3][h][c];
  }
}

// ---------------------------------------------------------------------------
// K7: per (n,h,z) GEMM partials over one 64-j tile (z in 0..7):
// pav[z][nh][i][56] = alpha[i, z*64+j] @ [v|vp][j]. 1536 blocks (6/CU).
// Stride-66 A-tile -> float2 reads; B stays [j][56] b128 reads.
// ---------------------------------------------------------------------------
__global__ __launch_bounds__(256) void k_av(
    const float* __restrict__ lgal, const float* __restrict__ proj,
    const float* __restrict__ vpg, float* __restrict__ pav)
{
  const int ib = blockIdx.x * 64;
  const int nh = blockIdx.y;
  const int z  = blockIdx.z;
  const int jb = z*64;
  const int n = nh / H_, h = nh % H_, nL = n*L_;
  const int tid = threadIdx.x;
  __shared__ float as[64*66];
  __shared__ float bs[64*60];
  const int tx = tid & 15, ty = tid >> 4;
  const int i0 = ty*4, c0 = tx*4;
  for (int m = 0; m < 4; ++m) {
    int idx = m*256 + tid;
    int r = idx >> 4, jq = (idx & 15) * 4;
    float4 a = *(const float4*)(lgal + ((size_t)nh*L_ + ib + r)*L_ + jb + jq);
    as[r*66+jq]=a.x; as[r*66+jq+1]=a.y; as[r*66+jq+2]=a.z; as[r*66+jq+3]=a.w;
  }
  for (int m = 0; m < 4; ++m) {
    int idx = m*256 + tid;
    int j = idx >> 4, qq = idx & 15;
    if (qq < 14) {
      float4 v;
      if (qq < 8) v = *(const float4*)(proj + (size_t)(nL + jb + j)*POUT_ + 768 + h*32 + qq*4);
      else        v = *(const float4*)(vpg  + (size_t)(nL + jb + j)*288  + h*24 + (qq-8)*4);
      float* d = bs + j*60 + qq*4;
      d[0]=v.x; d[1]=v.y; d[2]=v.z; d[3]=v.w;
    }
  }
  __syncthreads();
  float acc[4][4] = {};
  #pragma unroll 4
  for (int k2 = 0; k2 < 64; k2 += 2) {
    float2 av[4];
    #pragma unroll
    for (int d = 0; d < 4; ++d) av[d] = *(const float2*)(as + (i0+d)*66 + k2);
    float4 bv0 = *(const float4*)(bs + (k2  )*60 + c0);
    float4 bv1 = *(const float4*)(bs + (k2+1)*60 + c0);
    #pragma unroll
    for (int a2 = 0; a2 < 4; ++a2) {
      acc[a2][0] += av[a2].x*bv0.x + av[a2].y*bv1.x;
      acc[a2][1] += av[a2].x*bv0.y + av[a2].y*bv1.y;
      acc[a2][2] += av[a2].x*bv0.z + av[a2].y*bv1.z;
      acc[a2][3] += av[a2].x*bv0.w + av[a2].y*bv1.w;
    }
  }
  if (c0 < 56) {
    #pragma unroll
    for (int a2 = 0; a2 < 4; ++a2)
      *(float4*)(pav + (((size_t)z*24 + nh)*L_ + ib + i0 + a2)*56 + c0) =
          make_float4(acc[a2][0], acc[a2][1], acc[a2][2], acc[a2][3]);
  }
}

// ---------------------------------------------------------------------------
// K8: reduce 8 k_av partials -> feat_node + fused point post-process
// ---------------------------------------------------------------------------
__global__ __launch_bounds__(256) void k_avred(
    const float* __restrict__ pav, const float* __restrict__ R,
    const float* __restrict__ coord, float* __restrict__ feat)
{
  const int tok = blockIdx.x, tid = threadIdx.x;
  const int n = tok / L_, i = tok % L_;
  __shared__ float ag[288];
  float* fb = feat + (size_t)tok*FEAT_;
  const size_t zstride = (size_t)24*L_*56;
  for (int u = tid; u < 672; u += 256) {
    int h = u / 56, c = u % 56;
    size_t base = (((size_t)(n*H_ + h))*L_ + i)*56 + c;
    float v = 0.f;
    #pragma unroll
    for (int zz = 0; zz < 8; ++zz) v += pav[base + zz*zstride];
    if (c < 32) fb[768 + h*32 + c] = v;
    else        ag[h*24 + (c - 32)] = v;
  }
  __syncthreads();
  if (tid < 96) {
    const float* Rm = R + (size_t)tok*9;
    const float cx = coord[(size_t)tok*3], cy = coord[(size_t)tok*3+1], cz = coord[(size_t)tok*3+2];
    float dx = ag[tid*3] - cx, dy = ag[tid*3+1] - cy, dz = ag[tid*3+2] - cz;
    float fx = Rm[0]*dx + Rm[3]*dy + Rm[6]*dz;
    float fy = Rm[1]*dx + Rm[4]*dy + Rm[7]*dz;
    float fz = Rm[2]*dx + Rm[5]*dy + Rm[8]*dz;
    float dist = sqrtf(fx*fx + fy*fy + fz*fz);
    float idn = 1.f/(dist + 1e-4f);
    fb[1152+tid*3]=fx; fb[1152+tid*3+1]=fy; fb[1152+tid*3+2]=fz;
    fb[1440+tid]=dist;
    fb[1536+tid*3]=fx*idn; fb[1536+tid*3+1]=fy*idn; fb[1536+tid*3+2]=fz*idn;
  }
}

// ---------------------------------------------------------------------------
// K9: y = feat @ Wout^T.  8 tokens x 64 outputs per block.
// ---------------------------------------------------------------------------
__global__ __launch_bounds__(256) void k_y_gemm(
    const float* __restrict__ feat, const float* __restrict__ Wout,
    float* __restrict__ ybuf)
{
  const int rb = blockIdx.x * 8;
  const int ob = blockIdx.y * 64;
  const int tid = threadIdx.x;
  __shared__ float wt[96*65];   // [k][out], padded
  __shared__ float ft[96*10];   // [k][tok], padded
  const int o = tid & 63, tg = tid >> 6;     // tokens tg*2, tg*2+1
  float acc0 = 0.f, acc1 = 0.f;
  for (int kb = 0; kb < FEAT_; kb += 96) {
    for (int m = 0; m < 6; ++m) {
      int idx = m*256 + tid;
      int r = idx / 24, cq = (idx % 24) * 4;
      float4 v = *(const float4*)(Wout + (size_t)(ob + r)*FEAT_ + kb + cq);
      wt[(cq  )*65 + r] = v.x;
      wt[(cq+1)*65 + r] = v.y;
      wt[(cq+2)*65 + r] = v.z;
      wt[(cq+3)*65 + r] = v.w;
    }
    if (tid < 192) {
      int t = tid / 24, cq = (tid % 24) * 4;
      float4 v = *(const float4*)(feat + (size_t)(rb + t)*FEAT_ + kb + cq);
      ft[(cq  )*10 + t] = v.x;
      ft[(cq+1)*10 + t] = v.y;
      ft[(cq+2)*10 + t] = v.z;
      ft[(cq+3)*10 + t] = v.w;
    }
    __syncthreads();
    #pragma unroll 4
    for (int k2 = 0; k2 < 96; ++k2) {
      float wv = wt[k2*65 + o];
      float2 fv = *(const float2*)(ft + k2*10 + tg*2);
      acc0 += wv * fv.x;
      acc1 += wv * fv.y;
    }
    __syncthreads();
  }
  ybuf[(size_t)(rb + tg*2    )*RD_ + ob + o] = acc0;
  ybuf[(size_t)(rb + tg*2 + 1)*RD_ + ob + o] = acc1;
}

// ---------------------------------------------------------------------------
// K10: per token: bias/mask/residual + LN1 + MLP + LN2
// ---------------------------------------------------------------------------
__device__ __forceinline__ float bsum128(float v, float* red, int tid) {
  #pragma unroll
  for (int off = 1; off < 64; off <<= 1) v += __shfl_xor(v, off, 64);
  __syncthreads();
  if ((tid & 63) == 0) red[tid >> 6] = v;
  __syncthreads();
  return red[0] + red[1];
}

__global__ __launch_bounds__(128) void k_mlp(
    const float* __restrict__ resf, const int* __restrict__ mask,
    const float* __restrict__ ybuf, const float* __restrict__ bout,
    const float* __restrict__ Wm1, const float* __restrict__ bm1,
    const float* __restrict__ Wm2, const float* __restrict__ bm2,
    const float* __restrict__ Wm3, const float* __restrict__ bm3,
    const float* __restrict__ g1, const float* __restrict__ b1,
    const float* __restrict__ g2, const float* __restrict__ b2,
    float* __restrict__ out)
{
  const int t = blockIdx.x, tid = threadIdx.x;
  __shared__ float xb[RD_], h1b[RD_], h2b[RD_];
  __shared__ float red[2];
  float acc = ybuf[(size_t)t*RD_ + tid] + bout[tid];
  if (mask[t] == 0) acc = 0.f;
  float r = resf[(size_t)t*RD_ + tid] + acc;

  float mean = bsum128(r, red, tid) * (1.f/RD_);
  float d = r - mean;
  float var = bsum128(d*d, red, tid) * (1.f/RD_);
  float xn = d * rsqrtf(var + 1e-5f) * g1[tid] + b1[tid];
  xb[tid] = xn;
  __syncthreads();

  float a1 = bm1[tid];
  {
    const float4* w4 = (const float4*)(Wm1 + (size_t)tid*RD_);
    #pragma unroll
    for (int c = 0; c < RD_/4; ++c) { float4 a = w4[c]; a1 += a.x*xb[4*c]+a.y*xb[4*c+1]+a.z*xb[4*c+2]+a.w*xb[4*c+3]; }
  }
  a1 = fmaxf(a1, 0.f);
  h1b[tid] = a1;
  __syncthreads();

  float a2 = bm2[tid];
  {
    const float4* w4 = (const float4*)(Wm2 + (size_t)tid*RD_);
    #pragma unroll
    for (int c = 0; c < RD_/4; ++c) { float4 a = w4[c]; a2 += a.x*h1b[4*c]+a.y*h1b[4*c+1]+a.z*h1b[4*c+2]+a.w*h1b[4*c+3]; }
  }
  a2 = fmaxf(a2, 0.f);
  h2b[tid] = a2;
  __syncthreads();

  float a3 = bm3[tid];
  {
    const float4* w4 = (const float4*)(Wm3 + (size_t)tid*RD_);
    #pragma unroll
    for (int c = 0; c < RD_/4; ++c) { float4 a = w4[c]; a3 += a.x*h2b[4*c]+a.y*h2b[4*c+1]+a.z*h2b[4*c+2]+a.w*h2b[4*c+3]; }
  }
  float r2 = xn + a3;
  float mean2 = bsum128(r2, red, tid) * (1.f/RD_);
  float d2 = r2 - mean2;
  float var2 = bsum128(d2*d2, red, tid) * (1.f/RD_);
  out[(size_t)t*RD_ + tid] = d2 * rsqrtf(var2 + 1e-5f) * g2[tid] + b2[tid];
}

// ---------------------------------------------------------------------------
extern "C" void kernel_launch(void* const* d_in, const int* in_sizes, int n_in,
                              void* d_out, int out_size, void* d_ws, size_t ws_size,
                              hipStream_t stream) {
  (void)in_sizes; (void)n_in; (void)out_size; (void)ws_size;
  const float* R     = (const float*)d_in[0];
  const float* coord = (const float*)d_in[1];
  const float* resf  = (const float*)d_in[2];
  const float* pair  = (const float*)d_in[3];
  const int*   mask  = (const int*)  d_in[4];
  const float* Wq    = (const float*)d_in[5];
  const float* Wk    = (const float*)d_in[6];
  const float* Wv    = (const float*)d_in[7];
  const float* Wpb   = (const float*)d_in[8];
  const float* spc   = (const float*)d_in[9];
  const float* Wqp   = (const float*)d_in[10];
  const float* Wkp   = (const float*)d_in[11];
  const float* Wvp   = (const float*)d_in[12];
  const float* Wout  = (const float*)d_in[13];
  const float* bout  = (const float*)d_in[14];
  const float* Wm1   = (const float*)d_in[15];
  const float* bm1   = (const float*)d_in[16];
  const float* Wm2   = (const float*)d_in[17];
  const float* bm2   = (const float*)d_in[18];
  const float* Wm3   = (const float*)d_in[19];
  const float* bm3   = (const float*)d_in[20];
  const float* g1    = (const float*)d_in[21];
  const float* b1    = (const float*)d_in[22];
  const float* g2    = (const float*)d_in[23];
  const float* b2    = (const float*)d_in[24];

  float* ws   = (float*)d_ws;
  float* proj = ws;                               // NL*2016
  float* qt   = proj + (size_t)NL_*POUT_;         // 24*512*64
  float* kt   = qt   + (size_t)N_*H_*L_*64;       // 24*512*64
  float* vpg  = kt   + (size_t)N_*H_*L_*64;       // NL*288
  float* lgal = vpg  + (size_t)NL_*288;           // 24*512*512 (logits -> alpha)
  float* feat = lgal + (size_t)N_*H_*L_*L_;       // NL*1824
  float* ybuf = feat + (size_t)NL_*FEAT_;         // NL*128
  float* pav  = ybuf + (size_t)NL_*RD_;           // 8*24*512*56 (22MB)

  k_proj_gemm<<<dim3(NL_/8, 16), 256, 0, stream>>>(resf, Wq, Wk, Wv, Wqp, Wkp, Wvp, proj);
  k_rot<<<NL_, 64, 0, stream>>>(R, coord, spc, proj, qt, kt, vpg);
  k_lgns<<<dim3(L_/64, L_/64, N_*H_), 256, 0, stream>>>(qt, kt, lgal);
  k_pbias<<<dim3(L_/128, L_, N_), 256, 0, stream>>>(pair, mask, Wpb, lgal);
  k_softx<<<(N_*H_*L_)/4, 256, 0, stream>>>(mask, lgal);
  k_paggr<<<dim3(L_, N_), 256, 0, stream>>>(pair, lgal, feat);
  k_av<<<dim3(L_/64, N_*H_, 8), 256, 0, stream>>>(lgal, proj, vpg, pav);
  k_avred<<<NL_, 256, 0, stream>>>(pav, R, coord, feat);
  k_y_gemm<<<dim3(NL_/8, 2), 256, 0, stream>>>(feat, Wout, ybuf);
  k_mlp<<<NL_, 128, 0, stream>>>(resf, mask, ybuf, bout, Wm1, bm1, Wm2, bm2, Wm3, bm3,
                                 g1, b1, g2, b2, (float*)d_out);
}